// Round 5
// baseline (3208.953 us; speedup 1.0000x reference)
//
#include <hip/hip_runtime.h>
#include <hip/hip_bf16.h>
#include <math.h>

#define HH 4
#define CC 32
#define HC 128   // H*C
#define GG 64

// ---------------- batch weight transpose: W[K][C] -> WT[C][K] ----------------
struct TransArgs {
    const float* in[8];
    float* out[8];
    int K[8], C[8];
};

__global__ void transpose_kernel(TransArgs a) {
    int z = blockIdx.z;
    const float* in = a.in[z];
    float* out = a.out[z];
    int K = a.K[z], C = a.C[z];
    int c0 = blockIdx.x * 32, k0 = blockIdx.y * 32;
    if (c0 >= C || k0 >= K) return;
    __shared__ float t[32][33];
    int tx = threadIdx.x & 31, ty = threadIdx.x >> 5;   // 32 x 8
    #pragma unroll
    for (int i = 0; i < 4; ++i) {
        int kk = k0 + ty + i * 8, cc = c0 + tx;
        if (kk < K && cc < C) t[ty + i * 8][tx] = in[(size_t)kk * C + cc];
    }
    __syncthreads();
    #pragma unroll
    for (int i = 0; i < 4; ++i) {
        int cc = c0 + ty + i * 8, kk = k0 + tx;
        if (cc < C && kk < K) out[(size_t)cc * K + kk] = t[tx][ty + i * 8];
    }
}

// ---------------- QKV + skip projection: tiled GEMM (WT operand) ----------------
// grid = (ceil(N/128), 4); ct 0/1/2 -> q/k/v (128 cols, 8x8 thread tile),
// ct 3 -> skip (32 cols, 4x4 thread tile). K-tiles of 32.
// xs: [128][40] pad (write 2-way, read broadcast). wt: [rows][32] with float4-slot
// XOR swizzle kk4 ^ ((row>>3)&7) -> <=2-way on stage-write and compute-read.
template<int FIN>
__global__ __launch_bounds__(256, 4) void qkv_gemm_kernel(
    const float* __restrict__ x,
    const float* __restrict__ WqT, const float* __restrict__ bq,
    const float* __restrict__ WkT, const float* __restrict__ bk,
    const float* __restrict__ WvT, const float* __restrict__ bv,
    const float* __restrict__ WsT, const float* __restrict__ bs,
    float* __restrict__ q, float* __restrict__ k, float* __restrict__ v,
    float* __restrict__ skip, int N)
{
    __shared__ float xs[128 * 40];
    __shared__ float wt[128 * 32];

    const int tid = threadIdx.x;
    const int n0 = blockIdx.x * 128;
    const int ct = blockIdx.y;

    const float *WT, *b; float* out;
    if      (ct == 0) { WT = WqT; b = bq; out = q; }
    else if (ct == 1) { WT = WkT; b = bk; out = k; }
    else if (ct == 2) { WT = WvT; b = bv; out = v; }
    else              { WT = WsT; b = bs; out = skip; }

    constexpr int T = FIN / 32;

    if (ct < 3) {
        const int tc = tid & 15, tn = tid >> 4;
        float acc[8][8];
        #pragma unroll
        for (int r = 0; r < 8; ++r)
            #pragma unroll
            for (int c = 0; c < 8; ++c) acc[r][c] = 0.f;

        for (int t = 0; t < T; ++t) {
            if (t) __syncthreads();
            #pragma unroll
            for (int rr = 0; rr < 4; ++rr) {
                int lin = tid + rr * 256;
                int nl = lin >> 3, k4 = lin & 7;
                int node = n0 + nl;
                float4 xv = (node < N)
                    ? *(const float4*)&x[(size_t)node * FIN + t * 32 + k4 * 4]
                    : make_float4(0.f, 0.f, 0.f, 0.f);
                *(float4*)&xs[nl * 40 + k4 * 4] = xv;
            }
            #pragma unroll
            for (int rr = 0; rr < 4; ++rr) {
                int lin = tid + rr * 256;
                int c = lin >> 3, kk4 = lin & 7;
                float4 wv = *(const float4*)&WT[(size_t)c * FIN + t * 32 + kk4 * 4];
                *(float4*)&wt[c * 32 + ((kk4 ^ ((c >> 3) & 7)) * 4)] = wv;
            }
            __syncthreads();

            #pragma unroll
            for (int kk4 = 0; kk4 < 8; ++kk4) {
                float4 wa[8];
                #pragma unroll
                for (int c = 0; c < 8; ++c)
                    wa[c] = *(const float4*)&wt[(tc * 8 + c) * 32 + ((kk4 ^ (tc & 7)) * 4)];
                #pragma unroll
                for (int r = 0; r < 8; ++r) {
                    float4 xa = *(const float4*)&xs[(tn * 8 + r) * 40 + kk4 * 4];
                    #pragma unroll
                    for (int c = 0; c < 8; ++c)
                        acc[r][c] += xa.x * wa[c].x + xa.y * wa[c].y
                                   + xa.z * wa[c].z + xa.w * wa[c].w;
                }
            }
        }

        float4 b0 = *(const float4*)&b[tc * 8];
        float4 b1 = *(const float4*)&b[tc * 8 + 4];
        #pragma unroll
        for (int r = 0; r < 8; ++r) {
            int node = n0 + tn * 8 + r;
            if (node < N) {
                float4 o0, o1;
                o0.x = acc[r][0] + b0.x; o0.y = acc[r][1] + b0.y;
                o0.z = acc[r][2] + b0.z; o0.w = acc[r][3] + b0.w;
                o1.x = acc[r][4] + b1.x; o1.y = acc[r][5] + b1.y;
                o1.z = acc[r][6] + b1.z; o1.w = acc[r][7] + b1.w;
                *(float4*)&out[(size_t)node * 128 + tc * 8]     = o0;
                *(float4*)&out[(size_t)node * 128 + tc * 8 + 4] = o1;
            }
        }
    } else {
        const int tc = tid & 7, tn = tid >> 3;   // 8 col-groups x 4, 32 node-groups x 4
        float acc[4][4];
        #pragma unroll
        for (int r = 0; r < 4; ++r)
            #pragma unroll
            for (int c = 0; c < 4; ++c) acc[r][c] = 0.f;

        for (int t = 0; t < T; ++t) {
            if (t) __syncthreads();
            #pragma unroll
            for (int rr = 0; rr < 4; ++rr) {
                int lin = tid + rr * 256;
                int nl = lin >> 3, k4 = lin & 7;
                int node = n0 + nl;
                float4 xv = (node < N)
                    ? *(const float4*)&x[(size_t)node * FIN + t * 32 + k4 * 4]
                    : make_float4(0.f, 0.f, 0.f, 0.f);
                *(float4*)&xs[nl * 40 + k4 * 4] = xv;
            }
            {
                int c = tid >> 3, kk4 = tid & 7;   // 32 rows x 8 slots
                float4 wv = *(const float4*)&WT[(size_t)c * FIN + t * 32 + kk4 * 4];
                *(float4*)&wt[c * 32 + ((kk4 ^ ((c >> 3) & 7)) * 4)] = wv;
            }
            __syncthreads();

            #pragma unroll
            for (int kk4 = 0; kk4 < 8; ++kk4) {
                float4 wa[4];
                #pragma unroll
                for (int c = 0; c < 4; ++c) {
                    int row = tc * 4 + c;
                    wa[c] = *(const float4*)&wt[row * 32 + ((kk4 ^ ((row >> 3) & 7)) * 4)];
                }
                #pragma unroll
                for (int r = 0; r < 4; ++r) {
                    float4 xa = *(const float4*)&xs[(tn * 4 + r) * 40 + kk4 * 4];
                    #pragma unroll
                    for (int c = 0; c < 4; ++c)
                        acc[r][c] += xa.x * wa[c].x + xa.y * wa[c].y
                                   + xa.z * wa[c].z + xa.w * wa[c].w;
                }
            }
        }

        float4 b0 = *(const float4*)&b[tc * 4];
        #pragma unroll
        for (int r = 0; r < 4; ++r) {
            int node = n0 + tn * 4 + r;
            if (node < N) {
                float4 o;
                o.x = acc[r][0] + b0.x; o.y = acc[r][1] + b0.y;
                o.z = acc[r][2] + b0.z; o.w = acc[r][3] + b0.w;
                *(float4*)&out[(size_t)node * 32 + tc * 4] = o;
            }
        }
    }
}

// ---------------- CSR build ----------------
__global__ void deg_kernel(const int* __restrict__ dst, int* __restrict__ deg, int E)
{
    int e = blockIdx.x * blockDim.x + threadIdx.x;
    if (e < E) atomicAdd(&deg[dst[e]], 1);
}

__global__ void bsum_kernel(const int* __restrict__ deg, int* __restrict__ bsum, int N)
{
    int base = blockIdx.x * 1024;
    int tid = threadIdx.x;  // 256
    int s = 0;
    for (int i = base + tid; i < base + 1024 && i < N; i += 256) s += deg[i];
    #pragma unroll
    for (int ofs = 32; ofs > 0; ofs >>= 1) s += __shfl_xor(s, ofs, 64);
    __shared__ int ws[4];
    int wid = tid >> 6;
    if ((tid & 63) == 0) ws[wid] = s;
    __syncthreads();
    if (tid == 0) bsum[blockIdx.x] = ws[0] + ws[1] + ws[2] + ws[3];
}

__global__ void bscan_kernel(int* __restrict__ bsum, int* __restrict__ off, int nb, int N)
{
    int i = threadIdx.x;   // 64
    int val = (i < nb) ? bsum[i] : 0;
    int v = val;
    #pragma unroll
    for (int ofs = 1; ofs < 64; ofs <<= 1) {
        int t = __shfl_up(v, ofs, 64);
        if (i >= ofs) v += t;
    }
    if (i < nb) bsum[i] = v - val;   // exclusive
    if (i == 63) off[N] = v;         // grand total
}

__global__ void scan2_kernel(const int* __restrict__ deg, const int* __restrict__ bsum,
                             int* __restrict__ off, int* __restrict__ cursor, int N)
{
    int base = blockIdx.x * 1024;
    int tid = threadIdx.x;          // 256
    int idx = base + tid * 4;
    int d0 = (idx     < N) ? deg[idx]     : 0;
    int d1 = (idx + 1 < N) ? deg[idx + 1] : 0;
    int d2 = (idx + 2 < N) ? deg[idx + 2] : 0;
    int d3 = (idx + 3 < N) ? deg[idx + 3] : 0;
    int tsum = d0 + d1 + d2 + d3;
    int v = tsum;
    int lane = tid & 63;
    #pragma unroll
    for (int ofs = 1; ofs < 64; ofs <<= 1) {
        int t = __shfl_up(v, ofs, 64);
        if (lane >= ofs) v += t;
    }
    __shared__ int wsum[4];
    int wid = tid >> 6;
    if (lane == 63) wsum[wid] = v;
    __syncthreads();
    int wbase = 0;
    for (int w = 0; w < wid; ++w) wbase += wsum[w];
    int excl = bsum[blockIdx.x] + wbase + (v - tsum);
    if (idx     < N) { off[idx]     = excl;                cursor[idx]     = excl; }
    if (idx + 1 < N) { off[idx + 1] = excl + d0;           cursor[idx + 1] = excl + d0; }
    if (idx + 2 < N) { off[idx + 2] = excl + d0 + d1;      cursor[idx + 2] = excl + d0 + d1; }
    if (idx + 3 < N) { off[idx + 3] = excl + d0 + d1 + d2; cursor[idx + 3] = excl + d0 + d1 + d2; }
}

__global__ void fill_kernel(const int* __restrict__ src, const int* __restrict__ dst,
                            int* __restrict__ cursor, int* __restrict__ esrc, int E)
{
    int e = blockIdx.x * blockDim.x + threadIdx.x;
    if (e < E) {
        int d = dst[e];
        int pos = atomicAdd(&cursor[d], 1);
        esrc[pos] = src[e];
    }
}

// ---------------- fused attention (per-dst gather; no-max softmax) ----------------
__global__ void attn_kernel(const float* __restrict__ q, const float* __restrict__ k,
    const float* __restrict__ v, const int* __restrict__ off, const int* __restrict__ esrc,
    const float* __restrict__ skip, float* __restrict__ hout, int relu)
{
    int n = blockIdx.x;
    int j = threadIdx.x;    // 0..127 : h = j>>5, c = j&31
    const float scale = 0.17677669529663687f;  // 1/sqrt(32)

    float qj = q[(size_t)n * HC + j] * scale;
    int beg = off[n], end = off[n + 1];

    float l = 0.f, acc = 0.f;
    int p = beg;
    for (; p + 2 <= end; p += 2) {
        int s0 = esrc[p], s1 = esrc[p + 1];
        float k0 = k[(size_t)s0 * HC + j];
        float k1 = k[(size_t)s1 * HC + j];
        float v0 = v[(size_t)s0 * HC + j];
        float v1 = v[(size_t)s1 * HC + j];
        float d0 = qj * k0, d1 = qj * k1;
        #pragma unroll
        for (int ofs = 16; ofs > 0; ofs >>= 1) {
            d0 += __shfl_xor(d0, ofs, 32);
            d1 += __shfl_xor(d1, ofs, 32);
        }
        float e0 = __expf(d0), e1 = __expf(d1);
        l += e0 + e1;
        acc = fmaf(e0, v0, acc);
        acc = fmaf(e1, v1, acc);
    }
    if (p < end) {
        int s0 = esrc[p];
        float k0 = k[(size_t)s0 * HC + j];
        float v0 = v[(size_t)s0 * HC + j];
        float d0 = qj * k0;
        #pragma unroll
        for (int ofs = 16; ofs > 0; ofs >>= 1) d0 += __shfl_xor(d0, ofs, 32);
        float e0 = __expf(d0);
        l += e0;
        acc = fmaf(e0, v0, acc);
    }

    __shared__ float red[HC];
    red[j] = acc / (l + 1e-16f);
    __syncthreads();
    if (j < CC) {
        float val = 0.25f * (red[j] + red[j + CC] + red[j + 2*CC] + red[j + 3*CC])
                  + skip[(size_t)n * CC + j];
        if (relu) val = fmaxf(val, 0.f);
        hout[(size_t)n * CC + j] = val;
    }
}

// ---------------- global mean pool (sorted-run accumulation) ----------------
__global__ void pool_kernel(const float* __restrict__ h, const int* __restrict__ batch,
    float* __restrict__ sums, float* __restrict__ cntf, int N)
{
    int c = threadIdx.x & 31;
    int tn = threadIdx.x >> 5;            // 0..7
    int n0 = blockIdx.x * 256;
    int nend = (n0 + 256 < N) ? n0 + 256 : N;
    float acc = 0.f, cnt = 0.f;
    int curg = -1;
    for (int n = n0 + tn; n < nend; n += 8) {
        int g = batch[n];
        if (g != curg) {
            if (curg >= 0) {
                unsafeAtomicAdd(&sums[curg * CC + c], acc);
                if (c == 0) unsafeAtomicAdd(&cntf[curg], cnt);
            }
            acc = 0.f; cnt = 0.f; curg = g;
        }
        acc += h[(size_t)n * CC + c];
        cnt += 1.f;
    }
    if (curg >= 0) {
        unsafeAtomicAdd(&sums[curg * CC + c], acc);
        if (c == 0) unsafeAtomicAdd(&cntf[curg], cnt);
    }
}

// ---------------- final linear ----------------
__global__ void final_lin_kernel(const float* __restrict__ sums, const float* __restrict__ cntf,
    const float* __restrict__ Wlin, const float* __restrict__ blin, float* __restrict__ out)
{
    int g = blockIdx.x;        // 64
    int j = threadIdx.x;       // 16
    float cnt = fmaxf(cntf[g], 1.0f);
    float acc = 0.f;
    #pragma unroll
    for (int c = 0; c < CC; ++c)
        acc += (sums[g * CC + c] / cnt) * Wlin[c * 16 + j];
    out[g * 16 + j] = acc + blin[j];
}

extern "C" void kernel_launch(void* const* d_in, const int* in_sizes, int n_in,
                              void* d_out, int out_size, void* d_ws, size_t ws_size,
                              hipStream_t stream) {
    const float* x     = (const float*)d_in[0];
    const int*   ei    = (const int*)d_in[1];
    const int*   batch = (const int*)d_in[2];
    const float* Wq1 = (const float*)d_in[3],  *bq1 = (const float*)d_in[4];
    const float* Wk1 = (const float*)d_in[5],  *bk1 = (const float*)d_in[6];
    const float* Wv1 = (const float*)d_in[7],  *bv1 = (const float*)d_in[8];
    const float* Ws1 = (const float*)d_in[9],  *bs1 = (const float*)d_in[10];
    const float* Wq2 = (const float*)d_in[11], *bq2 = (const float*)d_in[12];
    const float* Wk2 = (const float*)d_in[13], *bk2 = (const float*)d_in[14];
    const float* Wv2 = (const float*)d_in[15], *bv2 = (const float*)d_in[16];
    const float* Ws2 = (const float*)d_in[17], *bs2 = (const float*)d_in[18];
    const float* Wlin = (const float*)d_in[19], *blin = (const float*)d_in[20];

    const int N = in_sizes[0] / 128;
    const int E = in_sizes[1] / 2;
    const int* src = ei;
    const int* dstp = ei + E;
    const int NB = (N + 1023) / 1024;

    // workspace carve (256B aligned)
    char* wp = (char*)d_ws;
    auto alloc = [&](size_t bytes) -> void* {
        void* p = wp;
        wp += (bytes + 255) & ~(size_t)255;
        return p;
    };
    float* q    = (float*)alloc((size_t)N * HC * 4);
    float* k    = (float*)alloc((size_t)N * HC * 4);
    float* v    = (float*)alloc((size_t)N * HC * 4);
    float* skip = (float*)alloc((size_t)N * CC * 4);
    float* h1   = (float*)alloc((size_t)N * CC * 4);
    float* h2   = (float*)alloc((size_t)N * CC * 4);
    int* deg    = (int*)alloc((size_t)N * 4);
    int* off    = (int*)alloc((size_t)(N + 1) * 4);
    int* cursor = (int*)alloc((size_t)N * 4);
    int* esrc   = (int*)alloc((size_t)E * 4);
    int* bsum   = (int*)alloc((size_t)((NB + 63) & ~63) * 4);
    float* sums = (float*)alloc((size_t)GG * CC * 4);
    float* cntf = (float*)alloc((size_t)GG * 4);
    float* wqT1 = (float*)alloc(128 * 128 * 4);
    float* wkT1 = (float*)alloc(128 * 128 * 4);
    float* wvT1 = (float*)alloc(128 * 128 * 4);
    float* wsT1 = (float*)alloc(32 * 128 * 4);
    float* wqT2 = (float*)alloc(128 * 32 * 4);
    float* wkT2 = (float*)alloc(128 * 32 * 4);
    float* wvT2 = (float*)alloc(128 * 32 * 4);
    float* wsT2 = (float*)alloc(32 * 32 * 4);

    // ---- weight transposes (one launch) ----
    TransArgs ta;
    ta.in[0] = Wq1; ta.out[0] = wqT1; ta.K[0] = 128; ta.C[0] = 128;
    ta.in[1] = Wk1; ta.out[1] = wkT1; ta.K[1] = 128; ta.C[1] = 128;
    ta.in[2] = Wv1; ta.out[2] = wvT1; ta.K[2] = 128; ta.C[2] = 128;
    ta.in[3] = Ws1; ta.out[3] = wsT1; ta.K[3] = 128; ta.C[3] = 32;
    ta.in[4] = Wq2; ta.out[4] = wqT2; ta.K[4] = 32;  ta.C[4] = 128;
    ta.in[5] = Wk2; ta.out[5] = wkT2; ta.K[5] = 32;  ta.C[5] = 128;
    ta.in[6] = Wv2; ta.out[6] = wvT2; ta.K[6] = 32;  ta.C[6] = 128;
    ta.in[7] = Ws2; ta.out[7] = wsT2; ta.K[7] = 32;  ta.C[7] = 32;
    transpose_kernel<<<dim3(4, 4, 8), 256, 0, stream>>>(ta);

    // ---- CSR build (once; shared by both layers) ----
    hipMemsetAsync(deg, 0, (size_t)N * 4, stream);
    deg_kernel<<<(E + 255) / 256, 256, 0, stream>>>(dstp, deg, E);
    bsum_kernel<<<NB, 256, 0, stream>>>(deg, bsum, N);
    bscan_kernel<<<1, 64, 0, stream>>>(bsum, off, NB, N);
    scan2_kernel<<<NB, 256, 0, stream>>>(deg, bsum, off, cursor, N);
    fill_kernel<<<(E + 255) / 256, 256, 0, stream>>>(src, dstp, cursor, esrc, E);

    dim3 ggrid((N + 127) / 128, 4);

    // ---- layer 1 ----
    qkv_gemm_kernel<128><<<ggrid, 256, 0, stream>>>(x, wqT1, bq1, wkT1, bk1, wvT1, bv1,
                                                    wsT1, bs1, q, k, v, skip, N);
    attn_kernel<<<N, 128, 0, stream>>>(q, k, v, off, esrc, skip, h1, 1);

    // ---- layer 2 ----
    qkv_gemm_kernel<32><<<ggrid, 256, 0, stream>>>(h1, wqT2, bq2, wkT2, bk2, wvT2, bv2,
                                                   wsT2, bs2, q, k, v, skip, N);
    attn_kernel<<<N, 128, 0, stream>>>(q, k, v, off, esrc, skip, h2, 0);

    // ---- pool + final linear ----
    hipMemsetAsync(sums, 0, (size_t)GG * CC * 4, stream);
    hipMemsetAsync(cntf, 0, (size_t)GG * 4, stream);
    pool_kernel<<<(N + 255) / 256, 256, 0, stream>>>(h2, batch, sums, cntf, N);
    final_lin_kernel<<<GG, 16, 0, stream>>>(sums, cntf, Wlin, blin, (float*)d_out);
}

// Round 6
// 799.279 us; speedup vs baseline: 4.0148x; 4.0148x over previous
//
#include <hip/hip_runtime.h>
#include <hip/hip_bf16.h>
#include <math.h>

#define HH 4
#define CC 32
#define HC 128   // H*C
#define GG 64

// ---------------- batch weight transpose: W[K][C] -> WT[C][K] ----------------
struct TransArgs {
    const float* in[8];
    float* out[8];
    int K[8], C[8];
};

__global__ void transpose_kernel(TransArgs a) {
    int z = blockIdx.z;
    const float* in = a.in[z];
    float* out = a.out[z];
    int K = a.K[z], C = a.C[z];
    int c0 = blockIdx.x * 32, k0 = blockIdx.y * 32;
    if (c0 >= C || k0 >= K) return;
    __shared__ float t[32][33];
    int tx = threadIdx.x & 31, ty = threadIdx.x >> 5;   // 32 x 8
    #pragma unroll
    for (int i = 0; i < 4; ++i) {
        int kk = k0 + ty + i * 8, cc = c0 + tx;
        if (kk < K && cc < C) t[ty + i * 8][tx] = in[(size_t)kk * C + cc];
    }
    __syncthreads();
    #pragma unroll
    for (int i = 0; i < 4; ++i) {
        int cc = c0 + ty + i * 8, kk = k0 + tx;
        if (cc < C && kk < K) out[(size_t)cc * K + kk] = t[tx][ty + i * 8];
    }
}

// ---------------- QKV + skip projection: tiled GEMM (WT operand) ----------------
// grid = (ceil(N/128), 4); ct 0/1/2 -> q/k/v (128 cols, 8x8 thread tile),
// ct 3 -> skip (32 cols, 4x4 thread tile). K-tiles of 32.
// Both LDS tiles: [row][8 float4-slots], slot XOR-swizzled by (row>>3)&7.
//   read xs : 16-lane broadcast, 4 tn-groups -> 4 distinct slots  (no conflict)
//   read wt : 16 tc-groups -> slots repeat 2x                    (2-way, free)
//   writes  : natural float4, 8 rows x 8 slots per wave          (min aliasing)
template<int FIN>
__global__ __launch_bounds__(256) void qkv_gemm_kernel(
    const float* __restrict__ x,
    const float* __restrict__ WqT, const float* __restrict__ bq,
    const float* __restrict__ WkT, const float* __restrict__ bk,
    const float* __restrict__ WvT, const float* __restrict__ bv,
    const float* __restrict__ WsT, const float* __restrict__ bs,
    float* __restrict__ q, float* __restrict__ k, float* __restrict__ v,
    float* __restrict__ skip, int N)
{
    __shared__ float xs[128 * 32];
    __shared__ float wt[128 * 32];

    const int tid = threadIdx.x;
    const int n0 = blockIdx.x * 128;
    const int ct = blockIdx.y;

    const float *WT, *b; float* out;
    if      (ct == 0) { WT = WqT; b = bq; out = q; }
    else if (ct == 1) { WT = WkT; b = bk; out = k; }
    else if (ct == 2) { WT = WvT; b = bv; out = v; }
    else              { WT = WsT; b = bs; out = skip; }

    constexpr int T = FIN / 32;

    if (ct < 3) {
        const int tc = tid & 15, tn = tid >> 4;
        float acc[8][8];
        #pragma unroll
        for (int r = 0; r < 8; ++r)
            #pragma unroll
            for (int c = 0; c < 8; ++c) acc[r][c] = 0.f;

        for (int t = 0; t < T; ++t) {
            if (t) __syncthreads();
            #pragma unroll
            for (int rr = 0; rr < 4; ++rr) {
                int lin = tid + rr * 256;
                int nl = lin >> 3, k4 = lin & 7;
                int node = n0 + nl;
                float4 xv = (node < N)
                    ? *(const float4*)&x[(size_t)node * FIN + t * 32 + k4 * 4]
                    : make_float4(0.f, 0.f, 0.f, 0.f);
                *(float4*)&xs[nl * 32 + ((k4 ^ ((nl >> 3) & 7)) * 4)] = xv;
            }
            #pragma unroll
            for (int rr = 0; rr < 4; ++rr) {
                int lin = tid + rr * 256;
                int c = lin >> 3, kk4 = lin & 7;
                float4 wv = *(const float4*)&WT[(size_t)c * FIN + t * 32 + kk4 * 4];
                *(float4*)&wt[c * 32 + ((kk4 ^ ((c >> 3) & 7)) * 4)] = wv;
            }
            __syncthreads();

            #pragma unroll
            for (int kk4 = 0; kk4 < 8; ++kk4) {
                float4 wa[8];
                #pragma unroll
                for (int c = 0; c < 8; ++c)
                    wa[c] = *(const float4*)&wt[(tc * 8 + c) * 32 + ((kk4 ^ (tc & 7)) * 4)];
                #pragma unroll
                for (int r = 0; r < 8; ++r) {
                    float4 xa = *(const float4*)&xs[(tn * 8 + r) * 32 + ((kk4 ^ (tn & 7)) * 4)];
                    #pragma unroll
                    for (int c = 0; c < 8; ++c)
                        acc[r][c] += xa.x * wa[c].x + xa.y * wa[c].y
                                   + xa.z * wa[c].z + xa.w * wa[c].w;
                }
            }
        }

        float4 b0 = *(const float4*)&b[tc * 8];
        float4 b1 = *(const float4*)&b[tc * 8 + 4];
        #pragma unroll
        for (int r = 0; r < 8; ++r) {
            int node = n0 + tn * 8 + r;
            if (node < N) {
                float4 o0, o1;
                o0.x = acc[r][0] + b0.x; o0.y = acc[r][1] + b0.y;
                o0.z = acc[r][2] + b0.z; o0.w = acc[r][3] + b0.w;
                o1.x = acc[r][4] + b1.x; o1.y = acc[r][5] + b1.y;
                o1.z = acc[r][6] + b1.z; o1.w = acc[r][7] + b1.w;
                *(float4*)&out[(size_t)node * 128 + tc * 8]     = o0;
                *(float4*)&out[(size_t)node * 128 + tc * 8 + 4] = o1;
            }
        }
    } else {
        const int tc = tid & 7, tn = tid >> 3;   // 8 col-groups x 4, 32 node-groups x 4
        float acc[4][4];
        #pragma unroll
        for (int r = 0; r < 4; ++r)
            #pragma unroll
            for (int c = 0; c < 4; ++c) acc[r][c] = 0.f;

        for (int t = 0; t < T; ++t) {
            if (t) __syncthreads();
            #pragma unroll
            for (int rr = 0; rr < 4; ++rr) {
                int lin = tid + rr * 256;
                int nl = lin >> 3, k4 = lin & 7;
                int node = n0 + nl;
                float4 xv = (node < N)
                    ? *(const float4*)&x[(size_t)node * FIN + t * 32 + k4 * 4]
                    : make_float4(0.f, 0.f, 0.f, 0.f);
                *(float4*)&xs[nl * 32 + ((k4 ^ ((nl >> 3) & 7)) * 4)] = xv;
            }
            {
                int c = tid >> 3, kk4 = tid & 7;   // 32 rows x 8 slots
                float4 wv = *(const float4*)&WT[(size_t)c * FIN + t * 32 + kk4 * 4];
                *(float4*)&wt[c * 32 + ((kk4 ^ ((c >> 3) & 7)) * 4)] = wv;
            }
            __syncthreads();

            #pragma unroll
            for (int kk4 = 0; kk4 < 8; ++kk4) {
                float4 wa[4];
                #pragma unroll
                for (int c = 0; c < 4; ++c) {
                    int row = tc * 4 + c;
                    wa[c] = *(const float4*)&wt[row * 32 + ((kk4 ^ ((row >> 3) & 7)) * 4)];
                }
                #pragma unroll
                for (int r = 0; r < 4; ++r) {
                    int row = tn * 4 + r;
                    float4 xa = *(const float4*)&xs[row * 32 + ((kk4 ^ ((row >> 3) & 7)) * 4)];
                    #pragma unroll
                    for (int c = 0; c < 4; ++c)
                        acc[r][c] += xa.x * wa[c].x + xa.y * wa[c].y
                                   + xa.z * wa[c].z + xa.w * wa[c].w;
                }
            }
        }

        float4 b0 = *(const float4*)&b[tc * 4];
        #pragma unroll
        for (int r = 0; r < 4; ++r) {
            int node = n0 + tn * 4 + r;
            if (node < N) {
                float4 o;
                o.x = acc[r][0] + b0.x; o.y = acc[r][1] + b0.y;
                o.z = acc[r][2] + b0.z; o.w = acc[r][3] + b0.w;
                *(float4*)&out[(size_t)node * 32 + tc * 4] = o;
            }
        }
    }
}

// ---------------- CSR build ----------------
__global__ void deg_kernel(const int* __restrict__ dst, int* __restrict__ deg, int E)
{
    int e = blockIdx.x * blockDim.x + threadIdx.x;
    if (e < E) atomicAdd(&deg[dst[e]], 1);
}

__global__ void bsum_kernel(const int* __restrict__ deg, int* __restrict__ bsum, int N)
{
    int base = blockIdx.x * 1024;
    int tid = threadIdx.x;  // 256
    int s = 0;
    for (int i = base + tid; i < base + 1024 && i < N; i += 256) s += deg[i];
    #pragma unroll
    for (int ofs = 32; ofs > 0; ofs >>= 1) s += __shfl_xor(s, ofs, 64);
    __shared__ int ws[4];
    int wid = tid >> 6;
    if ((tid & 63) == 0) ws[wid] = s;
    __syncthreads();
    if (tid == 0) bsum[blockIdx.x] = ws[0] + ws[1] + ws[2] + ws[3];
}

__global__ void bscan_kernel(int* __restrict__ bsum, int* __restrict__ off, int nb, int N)
{
    int i = threadIdx.x;   // 64
    int val = (i < nb) ? bsum[i] : 0;
    int v = val;
    #pragma unroll
    for (int ofs = 1; ofs < 64; ofs <<= 1) {
        int t = __shfl_up(v, ofs, 64);
        if (i >= ofs) v += t;
    }
    if (i < nb) bsum[i] = v - val;   // exclusive
    if (i == 63) off[N] = v;         // grand total
}

__global__ void scan2_kernel(const int* __restrict__ deg, const int* __restrict__ bsum,
                             int* __restrict__ off, int* __restrict__ cursor, int N)
{
    int base = blockIdx.x * 1024;
    int tid = threadIdx.x;          // 256
    int idx = base + tid * 4;
    int d0 = (idx     < N) ? deg[idx]     : 0;
    int d1 = (idx + 1 < N) ? deg[idx + 1] : 0;
    int d2 = (idx + 2 < N) ? deg[idx + 2] : 0;
    int d3 = (idx + 3 < N) ? deg[idx + 3] : 0;
    int tsum = d0 + d1 + d2 + d3;
    int v = tsum;
    int lane = tid & 63;
    #pragma unroll
    for (int ofs = 1; ofs < 64; ofs <<= 1) {
        int t = __shfl_up(v, ofs, 64);
        if (lane >= ofs) v += t;
    }
    __shared__ int wsum[4];
    int wid = tid >> 6;
    if (lane == 63) wsum[wid] = v;
    __syncthreads();
    int wbase = 0;
    for (int w = 0; w < wid; ++w) wbase += wsum[w];
    int excl = bsum[blockIdx.x] + wbase + (v - tsum);
    if (idx     < N) { off[idx]     = excl;                cursor[idx]     = excl; }
    if (idx + 1 < N) { off[idx + 1] = excl + d0;           cursor[idx + 1] = excl + d0; }
    if (idx + 2 < N) { off[idx + 2] = excl + d0 + d1;      cursor[idx + 2] = excl + d0 + d1; }
    if (idx + 3 < N) { off[idx + 3] = excl + d0 + d1 + d2; cursor[idx + 3] = excl + d0 + d1 + d2; }
}

__global__ void fill_kernel(const int* __restrict__ src, const int* __restrict__ dst,
                            int* __restrict__ cursor, int* __restrict__ esrc, int E)
{
    int e = blockIdx.x * blockDim.x + threadIdx.x;
    if (e < E) {
        int d = dst[e];
        int pos = atomicAdd(&cursor[d], 1);
        esrc[pos] = src[e];
    }
}

// ---------------- fused attention (per-dst gather; no-max softmax) ----------------
__global__ void attn_kernel(const float* __restrict__ q, const float* __restrict__ k,
    const float* __restrict__ v, const int* __restrict__ off, const int* __restrict__ esrc,
    const float* __restrict__ skip, float* __restrict__ hout, int relu)
{
    int n = blockIdx.x;
    int j = threadIdx.x;    // 0..127 : h = j>>5, c = j&31
    const float scale = 0.17677669529663687f;  // 1/sqrt(32)

    float qj = q[(size_t)n * HC + j] * scale;
    int beg = off[n], end = off[n + 1];

    float l = 0.f, acc = 0.f;
    int p = beg;
    for (; p + 2 <= end; p += 2) {
        int s0 = esrc[p], s1 = esrc[p + 1];
        float k0 = k[(size_t)s0 * HC + j];
        float k1 = k[(size_t)s1 * HC + j];
        float v0 = v[(size_t)s0 * HC + j];
        float v1 = v[(size_t)s1 * HC + j];
        float d0 = qj * k0, d1 = qj * k1;
        #pragma unroll
        for (int ofs = 16; ofs > 0; ofs >>= 1) {
            d0 += __shfl_xor(d0, ofs, 32);
            d1 += __shfl_xor(d1, ofs, 32);
        }
        float e0 = __expf(d0), e1 = __expf(d1);
        l += e0 + e1;
        acc = fmaf(e0, v0, acc);
        acc = fmaf(e1, v1, acc);
    }
    if (p < end) {
        int s0 = esrc[p];
        float k0 = k[(size_t)s0 * HC + j];
        float v0 = v[(size_t)s0 * HC + j];
        float d0 = qj * k0;
        #pragma unroll
        for (int ofs = 16; ofs > 0; ofs >>= 1) d0 += __shfl_xor(d0, ofs, 32);
        float e0 = __expf(d0);
        l += e0;
        acc = fmaf(e0, v0, acc);
    }

    __shared__ float red[HC];
    red[j] = acc / (l + 1e-16f);
    __syncthreads();
    if (j < CC) {
        float val = 0.25f * (red[j] + red[j + CC] + red[j + 2*CC] + red[j + 3*CC])
                  + skip[(size_t)n * CC + j];
        if (relu) val = fmaxf(val, 0.f);
        hout[(size_t)n * CC + j] = val;
    }
}

// ---------------- global mean pool (sorted-run accumulation) ----------------
__global__ void pool_kernel(const float* __restrict__ h, const int* __restrict__ batch,
    float* __restrict__ sums, float* __restrict__ cntf, int N)
{
    int c = threadIdx.x & 31;
    int tn = threadIdx.x >> 5;            // 0..7
    int n0 = blockIdx.x * 256;
    int nend = (n0 + 256 < N) ? n0 + 256 : N;
    float acc = 0.f, cnt = 0.f;
    int curg = -1;
    for (int n = n0 + tn; n < nend; n += 8) {
        int g = batch[n];
        if (g != curg) {
            if (curg >= 0) {
                unsafeAtomicAdd(&sums[curg * CC + c], acc);
                if (c == 0) unsafeAtomicAdd(&cntf[curg], cnt);
            }
            acc = 0.f; cnt = 0.f; curg = g;
        }
        acc += h[(size_t)n * CC + c];
        cnt += 1.f;
    }
    if (curg >= 0) {
        unsafeAtomicAdd(&sums[curg * CC + c], acc);
        if (c == 0) unsafeAtomicAdd(&cntf[curg], cnt);
    }
}

// ---------------- final linear ----------------
__global__ void final_lin_kernel(const float* __restrict__ sums, const float* __restrict__ cntf,
    const float* __restrict__ Wlin, const float* __restrict__ blin, float* __restrict__ out)
{
    int g = blockIdx.x;        // 64
    int j = threadIdx.x;       // 16
    float cnt = fmaxf(cntf[g], 1.0f);
    float acc = 0.f;
    #pragma unroll
    for (int c = 0; c < CC; ++c)
        acc += (sums[g * CC + c] / cnt) * Wlin[c * 16 + j];
    out[g * 16 + j] = acc + blin[j];
}

extern "C" void kernel_launch(void* const* d_in, const int* in_sizes, int n_in,
                              void* d_out, int out_size, void* d_ws, size_t ws_size,
                              hipStream_t stream) {
    const float* x     = (const float*)d_in[0];
    const int*   ei    = (const int*)d_in[1];
    const int*   batch = (const int*)d_in[2];
    const float* Wq1 = (const float*)d_in[3],  *bq1 = (const float*)d_in[4];
    const float* Wk1 = (const float*)d_in[5],  *bk1 = (const float*)d_in[6];
    const float* Wv1 = (const float*)d_in[7],  *bv1 = (const float*)d_in[8];
    const float* Ws1 = (const float*)d_in[9],  *bs1 = (const float*)d_in[10];
    const float* Wq2 = (const float*)d_in[11], *bq2 = (const float*)d_in[12];
    const float* Wk2 = (const float*)d_in[13], *bk2 = (const float*)d_in[14];
    const float* Wv2 = (const float*)d_in[15], *bv2 = (const float*)d_in[16];
    const float* Ws2 = (const float*)d_in[17], *bs2 = (const float*)d_in[18];
    const float* Wlin = (const float*)d_in[19], *blin = (const float*)d_in[20];

    const int N = in_sizes[0] / 128;
    const int E = in_sizes[1] / 2;
    const int* src = ei;
    const int* dstp = ei + E;
    const int NB = (N + 1023) / 1024;

    // workspace carve (256B aligned)
    char* wp = (char*)d_ws;
    auto alloc = [&](size_t bytes) -> void* {
        void* p = wp;
        wp += (bytes + 255) & ~(size_t)255;
        return p;
    };
    float* q    = (float*)alloc((size_t)N * HC * 4);
    float* k    = (float*)alloc((size_t)N * HC * 4);
    float* v    = (float*)alloc((size_t)N * HC * 4);
    float* skip = (float*)alloc((size_t)N * CC * 4);
    float* h1   = (float*)alloc((size_t)N * CC * 4);
    float* h2   = (float*)alloc((size_t)N * CC * 4);
    int* deg    = (int*)alloc((size_t)N * 4);
    int* off    = (int*)alloc((size_t)(N + 1) * 4);
    int* cursor = (int*)alloc((size_t)N * 4);
    int* esrc   = (int*)alloc((size_t)E * 4);
    int* bsum   = (int*)alloc((size_t)((NB + 63) & ~63) * 4);
    float* sums = (float*)alloc((size_t)GG * CC * 4);
    float* cntf = (float*)alloc((size_t)GG * 4);
    float* wqT1 = (float*)alloc(128 * 128 * 4);
    float* wkT1 = (float*)alloc(128 * 128 * 4);
    float* wvT1 = (float*)alloc(128 * 128 * 4);
    float* wsT1 = (float*)alloc(32 * 128 * 4);
    float* wqT2 = (float*)alloc(128 * 32 * 4);
    float* wkT2 = (float*)alloc(128 * 32 * 4);
    float* wvT2 = (float*)alloc(128 * 32 * 4);
    float* wsT2 = (float*)alloc(32 * 32 * 4);

    // ---- weight transposes (one launch) ----
    TransArgs ta;
    ta.in[0] = Wq1; ta.out[0] = wqT1; ta.K[0] = 128; ta.C[0] = 128;
    ta.in[1] = Wk1; ta.out[1] = wkT1; ta.K[1] = 128; ta.C[1] = 128;
    ta.in[2] = Wv1; ta.out[2] = wvT1; ta.K[2] = 128; ta.C[2] = 128;
    ta.in[3] = Ws1; ta.out[3] = wsT1; ta.K[3] = 128; ta.C[3] = 32;
    ta.in[4] = Wq2; ta.out[4] = wqT2; ta.K[4] = 32;  ta.C[4] = 128;
    ta.in[5] = Wk2; ta.out[5] = wkT2; ta.K[5] = 32;  ta.C[5] = 128;
    ta.in[6] = Wv2; ta.out[6] = wvT2; ta.K[6] = 32;  ta.C[6] = 128;
    ta.in[7] = Ws2; ta.out[7] = wsT2; ta.K[7] = 32;  ta.C[7] = 32;
    transpose_kernel<<<dim3(4, 4, 8), 256, 0, stream>>>(ta);

    // ---- CSR build (once; shared by both layers) ----
    hipMemsetAsync(deg, 0, (size_t)N * 4, stream);
    deg_kernel<<<(E + 255) / 256, 256, 0, stream>>>(dstp, deg, E);
    bsum_kernel<<<NB, 256, 0, stream>>>(deg, bsum, N);
    bscan_kernel<<<1, 64, 0, stream>>>(bsum, off, NB, N);
    scan2_kernel<<<NB, 256, 0, stream>>>(deg, bsum, off, cursor, N);
    fill_kernel<<<(E + 255) / 256, 256, 0, stream>>>(src, dstp, cursor, esrc, E);

    dim3 ggrid((N + 127) / 128, 4);

    // ---- layer 1 ----
    qkv_gemm_kernel<128><<<ggrid, 256, 0, stream>>>(x, wqT1, bq1, wkT1, bk1, wvT1, bv1,
                                                    wsT1, bs1, q, k, v, skip, N);
    attn_kernel<<<N, 128, 0, stream>>>(q, k, v, off, esrc, skip, h1, 1);

    // ---- layer 2 ----
    qkv_gemm_kernel<32><<<ggrid, 256, 0, stream>>>(h1, wqT2, bq2, wkT2, bk2, wvT2, bv2,
                                                   wsT2, bs2, q, k, v, skip, N);
    attn_kernel<<<N, 128, 0, stream>>>(q, k, v, off, esrc, skip, h2, 0);

    // ---- pool + final linear ----
    hipMemsetAsync(sums, 0, (size_t)GG * CC * 4, stream);
    hipMemsetAsync(cntf, 0, (size_t)GG * 4, stream);
    pool_kernel<<<(N + 255) / 256, 256, 0, stream>>>(h2, batch, sums, cntf, N);
    final_lin_kernel<<<GG, 16, 0, stream>>>(sums, cntf, Wlin, blin, (float*)d_out);
}

// Round 7
// 398.359 us; speedup vs baseline: 8.0554x; 2.0064x over previous
//
#include <hip/hip_runtime.h>
#include <hip/hip_bf16.h>
#include <math.h>

#define HH 4
#define CC 32
#define HC 128   // H*C
#define GG 64

// ---------------- transpose: in[R][C] -> out[C][ostride] ----------------
__global__ void transpose_kernel(const float* __restrict__ in, float* __restrict__ out,
                                 int R, int C, int ostride)
{
    int c0 = blockIdx.x * 32, r0 = blockIdx.y * 32;
    __shared__ float t[32][33];
    int tx = threadIdx.x & 31, ty = threadIdx.x >> 5;   // 32 x 8
    #pragma unroll
    for (int i = 0; i < 4; ++i) {
        int r = r0 + ty + i * 8, c = c0 + tx;
        if (r < R && c < C) t[ty + i * 8][tx] = in[(size_t)r * C + c];
    }
    __syncthreads();
    #pragma unroll
    for (int i = 0; i < 4; ++i) {
        int c = c0 + ty + i * 8, r = r0 + tx;
        if (c < C && r < R) out[(size_t)c * ostride + r] = t[tx][ty + i * 8];
    }
}

// ---------------- QKV + skip projection: tiled GEMM on pre-transposed x ----------------
// grid = (ceil(N/128), 7): ct 0,1=q[0:64),[64:128); 2,3=k; 4,5=v; 6=skip(32 cols)
// 256 threads; thread tile = 8 nodes (tn=tid>>4) x 4 cols (tc=tid&15). K-tiles of 32.
// xT: [FIN][Ns] pre-transposed -> stage [32][132] with natural float4 writes.
// W : original [FIN][OC]       -> stage [32][68] with natural float4 writes.
template<int FIN>
__global__ __launch_bounds__(256) void qkv_gemm_kernel(
    const float* __restrict__ xT, int Ns,
    const float* __restrict__ Wq, const float* __restrict__ bq,
    const float* __restrict__ Wk, const float* __restrict__ bk,
    const float* __restrict__ Wv, const float* __restrict__ bv,
    const float* __restrict__ Ws, const float* __restrict__ bs,
    float* __restrict__ q, float* __restrict__ k, float* __restrict__ v,
    float* __restrict__ skip, int N)
{
    __shared__ float xs[32 * 132];   // [kk][node] pad 132
    __shared__ float wt[32 * 68];    // [kk][col]  pad 68

    const int tid = threadIdx.x;
    const int tc = tid & 15, tn = tid >> 4;
    const int n0 = blockIdx.x * 128;
    const int ct = blockIdx.y;

    const float *W, *b; float* out;
    int wstride, c0;
    if (ct < 6) {
        int m = ct >> 1;
        c0 = (ct & 1) * 64;
        W = (m == 0 ? Wq : (m == 1 ? Wk : Wv));
        b = (m == 0 ? bq : (m == 1 ? bk : bv));
        out = (m == 0 ? q : (m == 1 ? k : v));
        wstride = HC;
    } else {
        W = Ws; b = bs; out = skip; wstride = CC; c0 = 0;
    }

    constexpr int T = FIN / 32;

    float acc[8][4];
    #pragma unroll
    for (int r = 0; r < 8; ++r)
        #pragma unroll
        for (int c = 0; c < 4; ++c) acc[r][c] = 0.f;

    for (int t = 0; t < T; ++t) {
        if (t) __syncthreads();
        // stage xT tile: natural float4 (rows are pre-transposed)
        #pragma unroll
        for (int rr = 0; rr < 4; ++rr) {
            int lin = tid + rr * 256;          // 0..1023
            int kk = lin >> 5, n4 = lin & 31;
            float4 xv = *(const float4*)&xT[(size_t)(t * 32 + kk) * Ns + n0 + n4 * 4];
            *(float4*)&xs[kk * 132 + n4 * 4] = xv;
        }
        // stage W tile: natural float4
        #pragma unroll
        for (int rr = 0; rr < 2; ++rr) {
            int lin = tid + rr * 256;          // 0..511
            int kk = lin >> 4, c4 = lin & 15;
            float4 wv = make_float4(0.f, 0.f, 0.f, 0.f);
            if (c0 + c4 * 4 < wstride)
                wv = *(const float4*)&W[(size_t)(t * 32 + kk) * wstride + c0 + c4 * 4];
            *(float4*)&wt[kk * 68 + c4 * 4] = wv;
        }
        __syncthreads();

        #pragma unroll
        for (int kk = 0; kk < 32; ++kk) {
            float4 wa = *(const float4*)&wt[kk * 68 + tc * 4];
            float4 xa = *(const float4*)&xs[kk * 132 + tn * 8];
            float4 xb = *(const float4*)&xs[kk * 132 + tn * 8 + 4];
            float xv[8] = {xa.x, xa.y, xa.z, xa.w, xb.x, xb.y, xb.z, xb.w};
            #pragma unroll
            for (int r = 0; r < 8; ++r) {
                acc[r][0] = fmaf(xv[r], wa.x, acc[r][0]);
                acc[r][1] = fmaf(xv[r], wa.y, acc[r][1]);
                acc[r][2] = fmaf(xv[r], wa.z, acc[r][2]);
                acc[r][3] = fmaf(xv[r], wa.w, acc[r][3]);
            }
        }
    }

    // epilogue
    if (c0 + tc * 4 < wstride) {
        float4 bb = *(const float4*)&b[c0 + tc * 4];
        #pragma unroll
        for (int r = 0; r < 8; ++r) {
            int node = n0 + tn * 8 + r;
            if (node < N) {
                float4 o;
                o.x = acc[r][0] + bb.x;
                o.y = acc[r][1] + bb.y;
                o.z = acc[r][2] + bb.z;
                o.w = acc[r][3] + bb.w;
                *(float4*)&out[(size_t)node * wstride + c0 + tc * 4] = o;
            }
        }
    }
}

// ---------------- CSR build ----------------
__global__ void deg_kernel(const int* __restrict__ dst, int* __restrict__ deg, int E)
{
    int e = blockIdx.x * blockDim.x + threadIdx.x;
    if (e < E) atomicAdd(&deg[dst[e]], 1);
}

__global__ void bsum_kernel(const int* __restrict__ deg, int* __restrict__ bsum, int N)
{
    int base = blockIdx.x * 1024;
    int tid = threadIdx.x;  // 256
    int s = 0;
    for (int i = base + tid; i < base + 1024 && i < N; i += 256) s += deg[i];
    #pragma unroll
    for (int ofs = 32; ofs > 0; ofs >>= 1) s += __shfl_xor(s, ofs, 64);
    __shared__ int ws[4];
    int wid = tid >> 6;
    if ((tid & 63) == 0) ws[wid] = s;
    __syncthreads();
    if (tid == 0) bsum[blockIdx.x] = ws[0] + ws[1] + ws[2] + ws[3];
}

__global__ void bscan_kernel(int* __restrict__ bsum, int* __restrict__ off, int nb, int N)
{
    int i = threadIdx.x;   // 64
    int val = (i < nb) ? bsum[i] : 0;
    int v = val;
    #pragma unroll
    for (int ofs = 1; ofs < 64; ofs <<= 1) {
        int t = __shfl_up(v, ofs, 64);
        if (i >= ofs) v += t;
    }
    if (i < nb) bsum[i] = v - val;   // exclusive
    if (i == 63) off[N] = v;         // grand total
}

__global__ void scan2_kernel(const int* __restrict__ deg, const int* __restrict__ bsum,
                             int* __restrict__ off, int* __restrict__ cursor, int N)
{
    int base = blockIdx.x * 1024;
    int tid = threadIdx.x;          // 256
    int idx = base + tid * 4;
    int d0 = (idx     < N) ? deg[idx]     : 0;
    int d1 = (idx + 1 < N) ? deg[idx + 1] : 0;
    int d2 = (idx + 2 < N) ? deg[idx + 2] : 0;
    int d3 = (idx + 3 < N) ? deg[idx + 3] : 0;
    int tsum = d0 + d1 + d2 + d3;
    int v = tsum;
    int lane = tid & 63;
    #pragma unroll
    for (int ofs = 1; ofs < 64; ofs <<= 1) {
        int t = __shfl_up(v, ofs, 64);
        if (lane >= ofs) v += t;
    }
    __shared__ int wsum[4];
    int wid = tid >> 6;
    if (lane == 63) wsum[wid] = v;
    __syncthreads();
    int wbase = 0;
    for (int w = 0; w < wid; ++w) wbase += wsum[w];
    int excl = bsum[blockIdx.x] + wbase + (v - tsum);
    if (idx     < N) { off[idx]     = excl;                cursor[idx]     = excl; }
    if (idx + 1 < N) { off[idx + 1] = excl + d0;           cursor[idx + 1] = excl + d0; }
    if (idx + 2 < N) { off[idx + 2] = excl + d0 + d1;      cursor[idx + 2] = excl + d0 + d1; }
    if (idx + 3 < N) { off[idx + 3] = excl + d0 + d1 + d2; cursor[idx + 3] = excl + d0 + d1 + d2; }
}

__global__ void fill_kernel(const int* __restrict__ src, const int* __restrict__ dst,
                            int* __restrict__ cursor, int* __restrict__ esrc, int E)
{
    int e = blockIdx.x * blockDim.x + threadIdx.x;
    if (e < E) {
        int d = dst[e];
        int pos = atomicAdd(&cursor[d], 1);
        esrc[pos] = src[e];
    }
}

// ---------------- fused attention (per-dst gather; no-max softmax) ----------------
__global__ void attn_kernel(const float* __restrict__ q, const float* __restrict__ k,
    const float* __restrict__ v, const int* __restrict__ off, const int* __restrict__ esrc,
    const float* __restrict__ skip, float* __restrict__ hout, int relu)
{
    int n = blockIdx.x;
    int j = threadIdx.x;    // 0..127 : h = j>>5, c = j&31
    const float scale = 0.17677669529663687f;  // 1/sqrt(32)

    float qj = q[(size_t)n * HC + j] * scale;
    int beg = off[n], end = off[n + 1];

    float l = 0.f, acc = 0.f;
    int p = beg;
    for (; p + 2 <= end; p += 2) {
        int s0 = esrc[p], s1 = esrc[p + 1];
        float k0 = k[(size_t)s0 * HC + j];
        float k1 = k[(size_t)s1 * HC + j];
        float v0 = v[(size_t)s0 * HC + j];
        float v1 = v[(size_t)s1 * HC + j];
        float d0 = qj * k0, d1 = qj * k1;
        #pragma unroll
        for (int ofs = 16; ofs > 0; ofs >>= 1) {
            d0 += __shfl_xor(d0, ofs, 32);
            d1 += __shfl_xor(d1, ofs, 32);
        }
        float e0 = __expf(d0), e1 = __expf(d1);
        l += e0 + e1;
        acc = fmaf(e0, v0, acc);
        acc = fmaf(e1, v1, acc);
    }
    if (p < end) {
        int s0 = esrc[p];
        float k0 = k[(size_t)s0 * HC + j];
        float v0 = v[(size_t)s0 * HC + j];
        float d0 = qj * k0;
        #pragma unroll
        for (int ofs = 16; ofs > 0; ofs >>= 1) d0 += __shfl_xor(d0, ofs, 32);
        float e0 = __expf(d0);
        l += e0;
        acc = fmaf(e0, v0, acc);
    }

    __shared__ float red[HC];
    red[j] = acc / (l + 1e-16f);
    __syncthreads();
    if (j < CC) {
        float val = 0.25f * (red[j] + red[j + CC] + red[j + 2*CC] + red[j + 3*CC])
                  + skip[(size_t)n * CC + j];
        if (relu) val = fmaxf(val, 0.f);
        hout[(size_t)n * CC + j] = val;
    }
}

// ---------------- global mean pool (sorted-run accumulation) ----------------
__global__ void pool_kernel(const float* __restrict__ h, const int* __restrict__ batch,
    float* __restrict__ sums, float* __restrict__ cntf, int N)
{
    int c = threadIdx.x & 31;
    int tn = threadIdx.x >> 5;            // 0..7
    int n0 = blockIdx.x * 256;
    int nend = (n0 + 256 < N) ? n0 + 256 : N;
    float acc = 0.f, cnt = 0.f;
    int curg = -1;
    for (int n = n0 + tn; n < nend; n += 8) {
        int g = batch[n];
        if (g != curg) {
            if (curg >= 0) {
                unsafeAtomicAdd(&sums[curg * CC + c], acc);
                if (c == 0) unsafeAtomicAdd(&cntf[curg], cnt);
            }
            acc = 0.f; cnt = 0.f; curg = g;
        }
        acc += h[(size_t)n * CC + c];
        cnt += 1.f;
    }
    if (curg >= 0) {
        unsafeAtomicAdd(&sums[curg * CC + c], acc);
        if (c == 0) unsafeAtomicAdd(&cntf[curg], cnt);
    }
}

// ---------------- final linear ----------------
__global__ void final_lin_kernel(const float* __restrict__ sums, const float* __restrict__ cntf,
    const float* __restrict__ Wlin, const float* __restrict__ blin, float* __restrict__ out)
{
    int g = blockIdx.x;        // 64
    int j = threadIdx.x;       // 16
    float cnt = fmaxf(cntf[g], 1.0f);
    float acc = 0.f;
    #pragma unroll
    for (int c = 0; c < CC; ++c)
        acc += (sums[g * CC + c] / cnt) * Wlin[c * 16 + j];
    out[g * 16 + j] = acc + blin[j];
}

extern "C" void kernel_launch(void* const* d_in, const int* in_sizes, int n_in,
                              void* d_out, int out_size, void* d_ws, size_t ws_size,
                              hipStream_t stream) {
    const float* x     = (const float*)d_in[0];
    const int*   ei    = (const int*)d_in[1];
    const int*   batch = (const int*)d_in[2];
    const float* Wq1 = (const float*)d_in[3],  *bq1 = (const float*)d_in[4];
    const float* Wk1 = (const float*)d_in[5],  *bk1 = (const float*)d_in[6];
    const float* Wv1 = (const float*)d_in[7],  *bv1 = (const float*)d_in[8];
    const float* Ws1 = (const float*)d_in[9],  *bs1 = (const float*)d_in[10];
    const float* Wq2 = (const float*)d_in[11], *bq2 = (const float*)d_in[12];
    const float* Wk2 = (const float*)d_in[13], *bk2 = (const float*)d_in[14];
    const float* Wv2 = (const float*)d_in[15], *bv2 = (const float*)d_in[16];
    const float* Ws2 = (const float*)d_in[17], *bs2 = (const float*)d_in[18];
    const float* Wlin = (const float*)d_in[19], *blin = (const float*)d_in[20];

    const int N = in_sizes[0] / 128;
    const int E = in_sizes[1] / 2;
    const int* src = ei;
    const int* dstp = ei + E;
    const int NB = (N + 1023) / 1024;
    const int Ns = (N + 127) & ~127;      // padded node stride for xT rows

    // workspace carve (256B aligned)
    char* wp = (char*)d_ws;
    auto alloc = [&](size_t bytes) -> void* {
        void* p = wp;
        wp += (bytes + 255) & ~(size_t)255;
        return p;
    };
    float* q    = (float*)alloc((size_t)N * HC * 4);
    float* k    = (float*)alloc((size_t)N * HC * 4);
    float* v    = (float*)alloc((size_t)N * HC * 4);
    float* skip = (float*)alloc((size_t)N * CC * 4);
    float* h1   = (float*)alloc((size_t)N * CC * 4);
    float* h2   = (float*)alloc((size_t)N * CC * 4);
    float* xT   = (float*)alloc((size_t)Ns * HC * 4);   // [128][Ns]
    float* h1T  = (float*)alloc((size_t)Ns * CC * 4);   // [32][Ns]
    int* deg    = (int*)alloc((size_t)N * 4);
    int* off    = (int*)alloc((size_t)(N + 1) * 4);
    int* cursor = (int*)alloc((size_t)N * 4);
    int* esrc   = (int*)alloc((size_t)E * 4);
    int* bsum   = (int*)alloc((size_t)((NB + 63) & ~63) * 4);
    float* sums = (float*)alloc((size_t)GG * CC * 4);
    float* cntf = (float*)alloc((size_t)GG * 4);

    const int RT = (N + 31) / 32;   // transpose row tiles

    // ---- CSR build (once; shared by both layers) ----
    hipMemsetAsync(deg, 0, (size_t)N * 4, stream);
    deg_kernel<<<(E + 255) / 256, 256, 0, stream>>>(dstp, deg, E);
    bsum_kernel<<<NB, 256, 0, stream>>>(deg, bsum, N);
    bscan_kernel<<<1, 64, 0, stream>>>(bsum, off, NB, N);
    scan2_kernel<<<NB, 256, 0, stream>>>(deg, bsum, off, cursor, N);
    fill_kernel<<<(E + 255) / 256, 256, 0, stream>>>(src, dstp, cursor, esrc, E);

    dim3 ggrid((N + 127) / 128, 7);

    // ---- layer 1 ----
    transpose_kernel<<<dim3(4, RT), 256, 0, stream>>>(x, xT, N, HC, Ns);
    qkv_gemm_kernel<128><<<ggrid, 256, 0, stream>>>(xT, Ns, Wq1, bq1, Wk1, bk1, Wv1, bv1,
                                                    Ws1, bs1, q, k, v, skip, N);
    attn_kernel<<<N, 128, 0, stream>>>(q, k, v, off, esrc, skip, h1, 1);

    // ---- layer 2 ----
    transpose_kernel<<<dim3(1, RT), 256, 0, stream>>>(h1, h1T, N, CC, Ns);
    qkv_gemm_kernel<32><<<ggrid, 256, 0, stream>>>(h1T, Ns, Wq2, bq2, Wk2, bk2, Wv2, bv2,
                                                   Ws2, bs2, q, k, v, skip, N);
    attn_kernel<<<N, 128, 0, stream>>>(q, k, v, off, esrc, skip, h2, 0);

    // ---- pool + final linear ----
    hipMemsetAsync(sums, 0, (size_t)GG * CC * 4, stream);
    hipMemsetAsync(cntf, 0, (size_t)GG * 4, stream);
    pool_kernel<<<(N + 255) / 256, 256, 0, stream>>>(h2, batch, sums, cntf, N);
    final_lin_kernel<<<GG, 16, 0, stream>>>(sums, cntf, Wlin, blin, (float*)d_out);
}

// Round 8
// 391.898 us; speedup vs baseline: 8.1882x; 1.0165x over previous
//
#include <hip/hip_runtime.h>
#include <hip/hip_bf16.h>
#include <hip/hip_fp16.h>
#include <math.h>

#define HH 4
#define CC 32
#define HC 128   // H*C
#define GG 64

// ---------------- transpose: in[R][C] -> out[C][ostride] ----------------
__global__ void transpose_kernel(const float* __restrict__ in, float* __restrict__ out,
                                 int R, int C, int ostride)
{
    int c0 = blockIdx.x * 32, r0 = blockIdx.y * 32;
    __shared__ float t[32][33];
    int tx = threadIdx.x & 31, ty = threadIdx.x >> 5;   // 32 x 8
    #pragma unroll
    for (int i = 0; i < 4; ++i) {
        int r = r0 + ty + i * 8, c = c0 + tx;
        if (r < R && c < C) t[ty + i * 8][tx] = in[(size_t)r * C + c];
    }
    __syncthreads();
    #pragma unroll
    for (int i = 0; i < 4; ++i) {
        int c = c0 + ty + i * 8, r = r0 + tx;
        if (c < C && r < R) out[(size_t)c * ostride + r] = t[tx][ty + i * 8];
    }
}

// ---------------- QKV + skip projection: tiled GEMM on pre-transposed x ----------------
template<int FIN>
__global__ __launch_bounds__(256) void qkv_gemm_kernel(
    const float* __restrict__ xT, int Ns,
    const float* __restrict__ Wq, const float* __restrict__ bq,
    const float* __restrict__ Wk, const float* __restrict__ bk,
    const float* __restrict__ Wv, const float* __restrict__ bv,
    const float* __restrict__ Ws, const float* __restrict__ bs,
    float* __restrict__ q, float* __restrict__ k, float* __restrict__ v,
    float* __restrict__ skip, int N)
{
    __shared__ float xs[32 * 132];   // [kk][node] pad 132
    __shared__ float wt[32 * 68];    // [kk][col]  pad 68

    const int tid = threadIdx.x;
    const int tc = tid & 15, tn = tid >> 4;
    const int n0 = blockIdx.x * 128;
    const int ct = blockIdx.y;

    const float *W, *b; float* out;
    int wstride, c0;
    if (ct < 6) {
        int m = ct >> 1;
        c0 = (ct & 1) * 64;
        W = (m == 0 ? Wq : (m == 1 ? Wk : Wv));
        b = (m == 0 ? bq : (m == 1 ? bk : bv));
        out = (m == 0 ? q : (m == 1 ? k : v));
        wstride = HC;
    } else {
        W = Ws; b = bs; out = skip; wstride = CC; c0 = 0;
    }

    constexpr int T = FIN / 32;

    float acc[8][4];
    #pragma unroll
    for (int r = 0; r < 8; ++r)
        #pragma unroll
        for (int c = 0; c < 4; ++c) acc[r][c] = 0.f;

    for (int t = 0; t < T; ++t) {
        if (t) __syncthreads();
        #pragma unroll
        for (int rr = 0; rr < 4; ++rr) {
            int lin = tid + rr * 256;          // 0..1023
            int kk = lin >> 5, n4 = lin & 31;
            float4 xv = *(const float4*)&xT[(size_t)(t * 32 + kk) * Ns + n0 + n4 * 4];
            *(float4*)&xs[kk * 132 + n4 * 4] = xv;
        }
        #pragma unroll
        for (int rr = 0; rr < 2; ++rr) {
            int lin = tid + rr * 256;          // 0..511
            int kk = lin >> 4, c4 = lin & 15;
            float4 wv = make_float4(0.f, 0.f, 0.f, 0.f);
            if (c0 + c4 * 4 < wstride)
                wv = *(const float4*)&W[(size_t)(t * 32 + kk) * wstride + c0 + c4 * 4];
            *(float4*)&wt[kk * 68 + c4 * 4] = wv;
        }
        __syncthreads();

        #pragma unroll
        for (int kk = 0; kk < 32; ++kk) {
            float4 wa = *(const float4*)&wt[kk * 68 + tc * 4];
            float4 xa = *(const float4*)&xs[kk * 132 + tn * 8];
            float4 xb = *(const float4*)&xs[kk * 132 + tn * 8 + 4];
            float xv[8] = {xa.x, xa.y, xa.z, xa.w, xb.x, xb.y, xb.z, xb.w};
            #pragma unroll
            for (int r = 0; r < 8; ++r) {
                acc[r][0] = fmaf(xv[r], wa.x, acc[r][0]);
                acc[r][1] = fmaf(xv[r], wa.y, acc[r][1]);
                acc[r][2] = fmaf(xv[r], wa.z, acc[r][2]);
                acc[r][3] = fmaf(xv[r], wa.w, acc[r][3]);
            }
        }
    }

    if (c0 + tc * 4 < wstride) {
        float4 bb = *(const float4*)&b[c0 + tc * 4];
        #pragma unroll
        for (int r = 0; r < 8; ++r) {
            int node = n0 + tn * 8 + r;
            if (node < N) {
                float4 o;
                o.x = acc[r][0] + bb.x;
                o.y = acc[r][1] + bb.y;
                o.z = acc[r][2] + bb.z;
                o.w = acc[r][3] + bb.w;
                *(float4*)&out[(size_t)node * wstride + c0 + tc * 4] = o;
            }
        }
    }
}

// ---------------- pack k,v (fp32) -> kv (half2: lo=k, hi=v) ----------------
__global__ void pack_kv_kernel(const float* __restrict__ k, const float* __restrict__ v,
                               __half2* __restrict__ kvp, int n)
{
    int i = blockIdx.x * 256 + threadIdx.x;
    if (i < n) kvp[i] = __floats2half2_rn(k[i], v[i]);
}

// ---------------- CSR build ----------------
__global__ void deg_kernel(const int* __restrict__ dst, int* __restrict__ deg, int E)
{
    int e = blockIdx.x * blockDim.x + threadIdx.x;
    if (e < E) atomicAdd(&deg[dst[e]], 1);
}

__global__ void bsum_kernel(const int* __restrict__ deg, int* __restrict__ bsum, int N)
{
    int base = blockIdx.x * 1024;
    int tid = threadIdx.x;  // 256
    int s = 0;
    for (int i = base + tid; i < base + 1024 && i < N; i += 256) s += deg[i];
    #pragma unroll
    for (int ofs = 32; ofs > 0; ofs >>= 1) s += __shfl_xor(s, ofs, 64);
    __shared__ int ws[4];
    int wid = tid >> 6;
    if ((tid & 63) == 0) ws[wid] = s;
    __syncthreads();
    if (tid == 0) bsum[blockIdx.x] = ws[0] + ws[1] + ws[2] + ws[3];
}

__global__ void bscan_kernel(int* __restrict__ bsum, int* __restrict__ off, int nb, int N)
{
    int i = threadIdx.x;   // 64
    int val = (i < nb) ? bsum[i] : 0;
    int v = val;
    #pragma unroll
    for (int ofs = 1; ofs < 64; ofs <<= 1) {
        int t = __shfl_up(v, ofs, 64);
        if (i >= ofs) v += t;
    }
    if (i < nb) bsum[i] = v - val;   // exclusive
    if (i == 63) off[N] = v;         // grand total
}

__global__ void scan2_kernel(const int* __restrict__ deg, const int* __restrict__ bsum,
                             int* __restrict__ off, int* __restrict__ cursor, int N)
{
    int base = blockIdx.x * 1024;
    int tid = threadIdx.x;          // 256
    int idx = base + tid * 4;
    int d0 = (idx     < N) ? deg[idx]     : 0;
    int d1 = (idx + 1 < N) ? deg[idx + 1] : 0;
    int d2 = (idx + 2 < N) ? deg[idx + 2] : 0;
    int d3 = (idx + 3 < N) ? deg[idx + 3] : 0;
    int tsum = d0 + d1 + d2 + d3;
    int v = tsum;
    int lane = tid & 63;
    #pragma unroll
    for (int ofs = 1; ofs < 64; ofs <<= 1) {
        int t = __shfl_up(v, ofs, 64);
        if (lane >= ofs) v += t;
    }
    __shared__ int wsum[4];
    int wid = tid >> 6;
    if (lane == 63) wsum[wid] = v;
    __syncthreads();
    int wbase = 0;
    for (int w = 0; w < wid; ++w) wbase += wsum[w];
    int excl = bsum[blockIdx.x] + wbase + (v - tsum);
    if (idx     < N) { off[idx]     = excl;                cursor[idx]     = excl; }
    if (idx + 1 < N) { off[idx + 1] = excl + d0;           cursor[idx + 1] = excl + d0; }
    if (idx + 2 < N) { off[idx + 2] = excl + d0 + d1;      cursor[idx + 2] = excl + d0 + d1; }
    if (idx + 3 < N) { off[idx + 3] = excl + d0 + d1 + d2; cursor[idx + 3] = excl + d0 + d1 + d2; }
}

__global__ void fill_kernel(const int* __restrict__ src, const int* __restrict__ dst,
                            int* __restrict__ cursor, int* __restrict__ esrc, int E)
{
    int e = blockIdx.x * blockDim.x + threadIdx.x;
    if (e < E) {
        int d = dst[e];
        int pos = atomicAdd(&cursor[d], 1);
        esrc[pos] = src[e];
    }
}

// ---------------- fused attention (per-dst gather; no-max softmax; half2 kv) ----------------
__global__ void attn_kernel(const float* __restrict__ q, const __half2* __restrict__ kvp,
    const int* __restrict__ off, const int* __restrict__ esrc,
    const float* __restrict__ skip, float* __restrict__ hout, int relu)
{
    int n = blockIdx.x;
    int j = threadIdx.x;    // 0..127 : h = j>>5, c = j&31
    const float scale = 0.17677669529663687f;  // 1/sqrt(32)

    float qj = q[(size_t)n * HC + j] * scale;
    int beg = off[n], end = off[n + 1];

    float l = 0.f, acc = 0.f;
    int p = beg;
    for (; p + 2 <= end; p += 2) {
        int s0 = esrc[p], s1 = esrc[p + 1];
        __half2 kv0 = kvp[(size_t)s0 * HC + j];
        __half2 kv1 = kvp[(size_t)s1 * HC + j];
        float k0 = __low2float(kv0), v0 = __high2float(kv0);
        float k1 = __low2float(kv1), v1 = __high2float(kv1);
        float d0 = qj * k0, d1 = qj * k1;
        #pragma unroll
        for (int ofs = 16; ofs > 0; ofs >>= 1) {
            d0 += __shfl_xor(d0, ofs, 32);
            d1 += __shfl_xor(d1, ofs, 32);
        }
        float e0 = __expf(d0), e1 = __expf(d1);
        l += e0 + e1;
        acc = fmaf(e0, v0, acc);
        acc = fmaf(e1, v1, acc);
    }
    if (p < end) {
        int s0 = esrc[p];
        __half2 kv0 = kvp[(size_t)s0 * HC + j];
        float k0 = __low2float(kv0), v0 = __high2float(kv0);
        float d0 = qj * k0;
        #pragma unroll
        for (int ofs = 16; ofs > 0; ofs >>= 1) d0 += __shfl_xor(d0, ofs, 32);
        float e0 = __expf(d0);
        l += e0;
        acc = fmaf(e0, v0, acc);
    }

    __shared__ float red[HC];
    red[j] = acc / (l + 1e-16f);
    __syncthreads();
    if (j < CC) {
        float val = 0.25f * (red[j] + red[j + CC] + red[j + 2*CC] + red[j + 3*CC])
                  + skip[(size_t)n * CC + j];
        if (relu) val = fmaxf(val, 0.f);
        hout[(size_t)n * CC + j] = val;
    }
}

// ---------------- global mean pool (sorted-run accumulation) ----------------
__global__ void pool_kernel(const float* __restrict__ h, const int* __restrict__ batch,
    float* __restrict__ sums, float* __restrict__ cntf, int N)
{
    int c = threadIdx.x & 31;
    int tn = threadIdx.x >> 5;            // 0..7
    int n0 = blockIdx.x * 256;
    int nend = (n0 + 256 < N) ? n0 + 256 : N;
    float acc = 0.f, cnt = 0.f;
    int curg = -1;
    for (int n = n0 + tn; n < nend; n += 8) {
        int g = batch[n];
        if (g != curg) {
            if (curg >= 0) {
                unsafeAtomicAdd(&sums[curg * CC + c], acc);
                if (c == 0) unsafeAtomicAdd(&cntf[curg], cnt);
            }
            acc = 0.f; cnt = 0.f; curg = g;
        }
        acc += h[(size_t)n * CC + c];
        cnt += 1.f;
    }
    if (curg >= 0) {
        unsafeAtomicAdd(&sums[curg * CC + c], acc);
        if (c == 0) unsafeAtomicAdd(&cntf[curg], cnt);
    }
}

// ---------------- final linear ----------------
__global__ void final_lin_kernel(const float* __restrict__ sums, const float* __restrict__ cntf,
    const float* __restrict__ Wlin, const float* __restrict__ blin, float* __restrict__ out)
{
    int g = blockIdx.x;        // 64
    int j = threadIdx.x;       // 16
    float cnt = fmaxf(cntf[g], 1.0f);
    float acc = 0.f;
    #pragma unroll
    for (int c = 0; c < CC; ++c)
        acc += (sums[g * CC + c] / cnt) * Wlin[c * 16 + j];
    out[g * 16 + j] = acc + blin[j];
}

extern "C" void kernel_launch(void* const* d_in, const int* in_sizes, int n_in,
                              void* d_out, int out_size, void* d_ws, size_t ws_size,
                              hipStream_t stream) {
    const float* x     = (const float*)d_in[0];
    const int*   ei    = (const int*)d_in[1];
    const int*   batch = (const int*)d_in[2];
    const float* Wq1 = (const float*)d_in[3],  *bq1 = (const float*)d_in[4];
    const float* Wk1 = (const float*)d_in[5],  *bk1 = (const float*)d_in[6];
    const float* Wv1 = (const float*)d_in[7],  *bv1 = (const float*)d_in[8];
    const float* Ws1 = (const float*)d_in[9],  *bs1 = (const float*)d_in[10];
    const float* Wq2 = (const float*)d_in[11], *bq2 = (const float*)d_in[12];
    const float* Wk2 = (const float*)d_in[13], *bk2 = (const float*)d_in[14];
    const float* Wv2 = (const float*)d_in[15], *bv2 = (const float*)d_in[16];
    const float* Ws2 = (const float*)d_in[17], *bs2 = (const float*)d_in[18];
    const float* Wlin = (const float*)d_in[19], *blin = (const float*)d_in[20];

    const int N = in_sizes[0] / 128;
    const int E = in_sizes[1] / 2;
    const int* src = ei;
    const int* dstp = ei + E;
    const int NB = (N + 1023) / 1024;
    const int Ns = (N + 127) & ~127;      // padded node stride for xT rows

    // workspace carve (256B aligned)
    char* wp = (char*)d_ws;
    auto alloc = [&](size_t bytes) -> void* {
        void* p = wp;
        wp += (bytes + 255) & ~(size_t)255;
        return p;
    };
    float* q    = (float*)alloc((size_t)N * HC * 4);
    float* k    = (float*)alloc((size_t)N * HC * 4);
    float* v    = (float*)alloc((size_t)N * HC * 4);
    float* skip = (float*)alloc((size_t)N * CC * 4);
    float* h1   = (float*)alloc((size_t)N * CC * 4);
    float* h2   = (float*)alloc((size_t)N * CC * 4);
    float* xT   = (float*)alloc((size_t)Ns * HC * 4);   // [128][Ns]; aliased by kvp after gemm
    float* h1T  = (float*)alloc((size_t)Ns * CC * 4);   // [32][Ns]
    int* deg    = (int*)alloc((size_t)N * 4);
    int* off    = (int*)alloc((size_t)(N + 1) * 4);
    int* cursor = (int*)alloc((size_t)N * 4);
    int* esrc   = (int*)alloc((size_t)E * 4);
    int* bsum   = (int*)alloc((size_t)((NB + 63) & ~63) * 4);
    float* sums = (float*)alloc((size_t)GG * CC * 4);
    float* cntf = (float*)alloc((size_t)GG * 4);

    // kv half2 pack aliases xT (xT only live during its gemm; kvp only during attn)
    __half2* kvp = (__half2*)xT;

    const int RT = (N + 31) / 32;   // transpose row tiles

    // ---- CSR build (once; shared by both layers) ----
    hipMemsetAsync(deg, 0, (size_t)N * 4, stream);
    deg_kernel<<<(E + 255) / 256, 256, 0, stream>>>(dstp, deg, E);
    bsum_kernel<<<NB, 256, 0, stream>>>(deg, bsum, N);
    bscan_kernel<<<1, 64, 0, stream>>>(bsum, off, NB, N);
    scan2_kernel<<<NB, 256, 0, stream>>>(deg, bsum, off, cursor, N);
    fill_kernel<<<(E + 255) / 256, 256, 0, stream>>>(src, dstp, cursor, esrc, E);

    dim3 ggrid((N + 127) / 128, 7);
    const int NP = N * HC;   // pack elements

    // ---- layer 1 ----
    transpose_kernel<<<dim3(4, RT), 256, 0, stream>>>(x, xT, N, HC, Ns);
    qkv_gemm_kernel<128><<<ggrid, 256, 0, stream>>>(xT, Ns, Wq1, bq1, Wk1, bk1, Wv1, bv1,
                                                    Ws1, bs1, q, k, v, skip, N);
    pack_kv_kernel<<<(NP + 255) / 256, 256, 0, stream>>>(k, v, kvp, NP);
    attn_kernel<<<N, 128, 0, stream>>>(q, kvp, off, esrc, skip, h1, 1);

    // ---- layer 2 ----
    transpose_kernel<<<dim3(1, RT), 256, 0, stream>>>(h1, h1T, N, CC, Ns);
    qkv_gemm_kernel<32><<<ggrid, 256, 0, stream>>>(h1T, Ns, Wq2, bq2, Wk2, bk2, Wv2, bv2,
                                                   Ws2, bs2, q, k, v, skip, N);
    pack_kv_kernel<<<(NP + 255) / 256, 256, 0, stream>>>(k, v, kvp, NP);
    attn_kernel<<<N, 128, 0, stream>>>(q, kvp, off, esrc, skip, h2, 0);

    // ---- pool + final linear ----
    hipMemsetAsync(sums, 0, (size_t)GG * CC * 4, stream);
    hipMemsetAsync(cntf, 0, (size_t)GG * 4, stream);
    pool_kernel<<<(N + 255) / 256, 256, 0, stream>>>(h2, batch, sums, cntf, N);
    final_lin_kernel<<<GG, 16, 0, stream>>>(sums, cntf, Wlin, blin, (float*)d_out);
}

// Round 10
// 316.031 us; speedup vs baseline: 10.1539x; 1.2401x over previous
//
#include <hip/hip_runtime.h>
#include <hip/hip_bf16.h>
#include <hip/hip_fp16.h>
#include <math.h>

#define HH 4
#define CC 32
#define HC 128   // H*C
#define GG 64

typedef _Float16 f16x2 __attribute__((ext_vector_type(2)));

__device__ __forceinline__ f16x2 u2h(unsigned u) {
    union { unsigned u; f16x2 h; } x; x.u = u; return x.h;
}
__device__ __forceinline__ unsigned pkh(float a, float b) {
    __half2 h = __floats2half2_rn(a, b);
    union { __half2 h; unsigned u; } x; x.h = h; return x.u;
}

// ---------------- transpose: in[R][C] -> out[C][ostride] ----------------
__global__ void transpose_kernel(const float* __restrict__ in, float* __restrict__ out,
                                 int R, int C, int ostride)
{
    int c0 = blockIdx.x * 32, r0 = blockIdx.y * 32;
    __shared__ float t[32][33];
    int tx = threadIdx.x & 31, ty = threadIdx.x >> 5;   // 32 x 8
    #pragma unroll
    for (int i = 0; i < 4; ++i) {
        int r = r0 + ty + i * 8, c = c0 + tx;
        if (r < R && c < C) t[ty + i * 8][tx] = in[(size_t)r * C + c];
    }
    __syncthreads();
    #pragma unroll
    for (int i = 0; i < 4; ++i) {
        int c = c0 + ty + i * 8, r = r0 + tx;
        if (c < C && r < R) out[(size_t)c * ostride + r] = t[tx][ty + i * 8];
    }
}

// ---------------- QKV + skip projection: tiled GEMM on pre-transposed x ----------------
// grid = (ceil(N/128), 7): ct 0,1 = q cols [0,64),[64,128) -> qh (half2 pairs)
//                          ct 2,3 = k -> kv2 slot .x ; ct 4,5 = v -> kv2 slot .y
//                          ct 6 = skip (fp32, only tc<8 valid)
template<int FIN>
__global__ __launch_bounds__(256) void qkv_gemm_kernel(
    const float* __restrict__ xT, int Ns,
    const float* __restrict__ Wq, const float* __restrict__ bq,
    const float* __restrict__ Wk, const float* __restrict__ bk,
    const float* __restrict__ Wv, const float* __restrict__ bv,
    const float* __restrict__ Ws, const float* __restrict__ bs,
    unsigned* __restrict__ qh, unsigned* __restrict__ kvw,
    float* __restrict__ skip, int N)
{
    __shared__ float xs[32 * 132];   // [kk][node] pad 132
    __shared__ float wt[32 * 68];    // [kk][col]  pad 68

    const int tid = threadIdx.x;
    const int tc = tid & 15, tn = tid >> 4;
    const int n0 = blockIdx.x * 128;
    const int ct = blockIdx.y;

    const float *W, *b;
    int wstride, c0;
    if (ct < 6) {
        int m = ct >> 1;
        c0 = (ct & 1) * 64;
        W = (m == 0 ? Wq : (m == 1 ? Wk : Wv));
        b = (m == 0 ? bq : (m == 1 ? bk : bv));
        wstride = HC;
    } else {
        W = Ws; b = bs; wstride = CC; c0 = 0;
    }

    constexpr int T = FIN / 32;

    float acc[8][4];
    #pragma unroll
    for (int r = 0; r < 8; ++r)
        #pragma unroll
        for (int c = 0; c < 4; ++c) acc[r][c] = 0.f;

    for (int t = 0; t < T; ++t) {
        if (t) __syncthreads();
        #pragma unroll
        for (int rr = 0; rr < 4; ++rr) {
            int lin = tid + rr * 256;          // 0..1023
            int kk = lin >> 5, n4 = lin & 31;
            float4 xv = *(const float4*)&xT[(size_t)(t * 32 + kk) * Ns + n0 + n4 * 4];
            *(float4*)&xs[kk * 132 + n4 * 4] = xv;
        }
        #pragma unroll
        for (int rr = 0; rr < 2; ++rr) {
            int lin = tid + rr * 256;          // 0..511
            int kk = lin >> 4, c4 = lin & 15;
            float4 wv = make_float4(0.f, 0.f, 0.f, 0.f);
            if (c0 + c4 * 4 < wstride)
                wv = *(const float4*)&W[(size_t)(t * 32 + kk) * wstride + c0 + c4 * 4];
            *(float4*)&wt[kk * 68 + c4 * 4] = wv;
        }
        __syncthreads();

        #pragma unroll
        for (int kk = 0; kk < 32; ++kk) {
            float4 wa = *(const float4*)&wt[kk * 68 + tc * 4];
            float4 xa = *(const float4*)&xs[kk * 132 + tn * 8];
            float4 xb = *(const float4*)&xs[kk * 132 + tn * 8 + 4];
            float xv[8] = {xa.x, xa.y, xa.z, xa.w, xb.x, xb.y, xb.z, xb.w};
            #pragma unroll
            for (int r = 0; r < 8; ++r) {
                acc[r][0] = fmaf(xv[r], wa.x, acc[r][0]);
                acc[r][1] = fmaf(xv[r], wa.y, acc[r][1]);
                acc[r][2] = fmaf(xv[r], wa.z, acc[r][2]);
                acc[r][3] = fmaf(xv[r], wa.w, acc[r][3]);
            }
        }
    }

    if (c0 + tc * 4 < wstride) {   // guard: skip tile only has 8 valid col-groups
        float4 bb = *(const float4*)&b[c0 + tc * 4];
        const int pi = c0 / 2 + tc * 2;    // half2-pair index (q/k/v)
        #pragma unroll
        for (int r = 0; r < 8; ++r) {
            int node = n0 + tn * 8 + r;
            if (node >= N) break;
            float o0 = acc[r][0] + bb.x, o1 = acc[r][1] + bb.y;
            float o2 = acc[r][2] + bb.z, o3 = acc[r][3] + bb.w;
            if (ct < 2) {
                *(uint2*)&qh[(size_t)node * 64 + pi] = make_uint2(pkh(o0, o1), pkh(o2, o3));
            } else if (ct < 4) {
                kvw[((size_t)node * 64 + pi) * 2]       = pkh(o0, o1);
                kvw[((size_t)node * 64 + pi + 1) * 2]   = pkh(o2, o3);
            } else if (ct < 6) {
                kvw[((size_t)node * 64 + pi) * 2 + 1]     = pkh(o0, o1);
                kvw[((size_t)node * 64 + pi + 1) * 2 + 1] = pkh(o2, o3);
            } else {
                *(float4*)&skip[(size_t)node * CC + tc * 4] = make_float4(o0, o1, o2, o3);
            }
        }
    }
}

// ---------------- CSR build ----------------
__global__ void deg_kernel(const int* __restrict__ dst, int* __restrict__ deg, int E)
{
    int e = blockIdx.x * blockDim.x + threadIdx.x;
    if (e < E) atomicAdd(&deg[dst[e]], 1);
}

__global__ void bsum_kernel(const int* __restrict__ deg, int* __restrict__ bsum, int N)
{
    int base = blockIdx.x * 1024;
    int tid = threadIdx.x;  // 256
    int s = 0;
    for (int i = base + tid; i < base + 1024 && i < N; i += 256) s += deg[i];
    #pragma unroll
    for (int ofs = 32; ofs > 0; ofs >>= 1) s += __shfl_xor(s, ofs, 64);
    __shared__ int ws[4];
    int wid = tid >> 6;
    if ((tid & 63) == 0) ws[wid] = s;
    __syncthreads();
    if (tid == 0) bsum[blockIdx.x] = ws[0] + ws[1] + ws[2] + ws[3];
}

__global__ void bscan_kernel(int* __restrict__ bsum, int* __restrict__ off, int nb, int N)
{
    int i = threadIdx.x;   // 64
    int val = (i < nb) ? bsum[i] : 0;
    int v = val;
    #pragma unroll
    for (int ofs = 1; ofs < 64; ofs <<= 1) {
        int t = __shfl_up(v, ofs, 64);
        if (i >= ofs) v += t;
    }
    if (i < nb) bsum[i] = v - val;   // exclusive
    if (i == 63) off[N] = v;         // grand total
}

__global__ void scan2_kernel(const int* __restrict__ deg, const int* __restrict__ bsum,
                             int* __restrict__ off, int* __restrict__ cursor, int N)
{
    int base = blockIdx.x * 1024;
    int tid = threadIdx.x;          // 256
    int idx = base + tid * 4;
    int d0 = (idx     < N) ? deg[idx]     : 0;
    int d1 = (idx + 1 < N) ? deg[idx + 1] : 0;
    int d2 = (idx + 2 < N) ? deg[idx + 2] : 0;
    int d3 = (idx + 3 < N) ? deg[idx + 3] : 0;
    int tsum = d0 + d1 + d2 + d3;
    int v = tsum;
    int lane = tid & 63;
    #pragma unroll
    for (int ofs = 1; ofs < 64; ofs <<= 1) {
        int t = __shfl_up(v, ofs, 64);
        if (lane >= ofs) v += t;
    }
    __shared__ int wsum[4];
    int wid = tid >> 6;
    if (lane == 63) wsum[wid] = v;
    __syncthreads();
    int wbase = 0;
    for (int w = 0; w < wid; ++w) wbase += wsum[w];
    int excl = bsum[blockIdx.x] + wbase + (v - tsum);
    if (idx     < N) { off[idx]     = excl;                cursor[idx]     = excl; }
    if (idx + 1 < N) { off[idx + 1] = excl + d0;           cursor[idx + 1] = excl + d0; }
    if (idx + 2 < N) { off[idx + 2] = excl + d0 + d1;      cursor[idx + 2] = excl + d0 + d1; }
    if (idx + 3 < N) { off[idx + 3] = excl + d0 + d1 + d2; cursor[idx + 3] = excl + d0 + d1 + d2; }
}

__global__ void fill_kernel(const int* __restrict__ src, const int* __restrict__ dst,
                            int* __restrict__ cursor, int* __restrict__ esrc, int E)
{
    int e = blockIdx.x * blockDim.x + threadIdx.x;
    if (e < E) {
        int d = dst[e];
        int pos = atomicAdd(&cursor[d], 1);
        esrc[pos] = src[e];
    }
}

// ---------------- fused attention: 1 wave per node ----------------
// lane = (head h = lane>>4, channel-pair c2 = lane&15). kv2[n][64] = {k2,v2} per pair.
__global__ __launch_bounds__(128) void attn_kernel(const unsigned* __restrict__ qh,
    const uint2* __restrict__ kv2, const int* __restrict__ off, const int* __restrict__ esrc,
    const float* __restrict__ skip, float* __restrict__ hout, int N, int relu)
{
    const int wave = threadIdx.x >> 6;
    const int lane = threadIdx.x & 63;
    const int n = blockIdx.x * 2 + wave;
    if (n >= N) return;
    const int c2 = lane & 15;
    const float scale = 0.17677669529663687f;  // 1/sqrt(32)

    f16x2 q2 = u2h(qh[(size_t)n * 64 + lane]);
    int beg = __builtin_amdgcn_readfirstlane(off[n]);
    int end = __builtin_amdgcn_readfirstlane(off[n + 1]);

    float lsum = 0.f, ax = 0.f, ay = 0.f;

    auto body = [&](uint2 raw) {
        f16x2 k2 = u2h(raw.x), v2 = u2h(raw.y);
#if defined(__has_builtin) && __has_builtin(__builtin_amdgcn_fdot2)
        float d = __builtin_amdgcn_fdot2(q2, k2, 0.f, false);
#else
        float d = (float)q2.x * (float)k2.x + (float)q2.y * (float)k2.y;
#endif
        d += __shfl_xor(d, 1, 16);
        d += __shfl_xor(d, 2, 16);
        d += __shfl_xor(d, 4, 16);
        d += __shfl_xor(d, 8, 16);
        float e = __expf(d * scale);
        lsum += e;
        ax = fmaf(e, (float)v2.x, ax);
        ay = fmaf(e, (float)v2.y, ay);
    };

    int p = beg;
    for (; p + 4 <= end; p += 4) {
        int s0 = esrc[p], s1 = esrc[p + 1], s2 = esrc[p + 2], s3 = esrc[p + 3];
        uint2 r0 = kv2[(size_t)s0 * 64 + lane];
        uint2 r1 = kv2[(size_t)s1 * 64 + lane];
        uint2 r2 = kv2[(size_t)s2 * 64 + lane];
        uint2 r3 = kv2[(size_t)s3 * 64 + lane];
        body(r0); body(r1); body(r2); body(r3);
    }
    for (; p < end; ++p) {
        int s0 = esrc[p];
        body(kv2[(size_t)s0 * 64 + lane]);
    }

    float inv = 1.f / (lsum + 1e-16f);
    float rx = ax * inv, ry = ay * inv;
    rx += __shfl_xor(rx, 16, 64);  ry += __shfl_xor(ry, 16, 64);
    rx += __shfl_xor(rx, 32, 64);  ry += __shfl_xor(ry, 32, 64);
    if (lane < 16) {
        float2 sk = *(const float2*)&skip[(size_t)n * CC + c2 * 2];
        float ox = 0.25f * rx + sk.x;
        float oy = 0.25f * ry + sk.y;
        if (relu) { ox = fmaxf(ox, 0.f); oy = fmaxf(oy, 0.f); }
        *(float2*)&hout[(size_t)n * CC + c2 * 2] = make_float2(ox, oy);
    }
}

// ---------------- global mean pool (sorted-run accumulation) ----------------
__global__ void pool_kernel(const float* __restrict__ h, const int* __restrict__ batch,
    float* __restrict__ sums, float* __restrict__ cntf, int N)
{
    int c = threadIdx.x & 31;
    int tn = threadIdx.x >> 5;            // 0..7
    int n0 = blockIdx.x * 256;
    int nend = (n0 + 256 < N) ? n0 + 256 : N;
    float acc = 0.f, cnt = 0.f;
    int curg = -1;
    for (int n = n0 + tn; n < nend; n += 8) {
        int g = batch[n];
        if (g != curg) {
            if (curg >= 0) {
                unsafeAtomicAdd(&sums[curg * CC + c], acc);
                if (c == 0) unsafeAtomicAdd(&cntf[curg], cnt);
            }
            acc = 0.f; cnt = 0.f; curg = g;
        }
        acc += h[(size_t)n * CC + c];
        cnt += 1.f;
    }
    if (curg >= 0) {
        unsafeAtomicAdd(&sums[curg * CC + c], acc);
        if (c == 0) unsafeAtomicAdd(&cntf[curg], cnt);
    }
}

// ---------------- final linear ----------------
__global__ void final_lin_kernel(const float* __restrict__ sums, const float* __restrict__ cntf,
    const float* __restrict__ Wlin, const float* __restrict__ blin, float* __restrict__ out)
{
    int g = blockIdx.x;        // 64
    int j = threadIdx.x;       // 16
    float cnt = fmaxf(cntf[g], 1.0f);
    float acc = 0.f;
    #pragma unroll
    for (int c = 0; c < CC; ++c)
        acc += (sums[g * CC + c] / cnt) * Wlin[c * 16 + j];
    out[g * 16 + j] = acc + blin[j];
}

extern "C" void kernel_launch(void* const* d_in, const int* in_sizes, int n_in,
                              void* d_out, int out_size, void* d_ws, size_t ws_size,
                              hipStream_t stream) {
    const float* x     = (const float*)d_in[0];
    const int*   ei    = (const int*)d_in[1];
    const int*   batch = (const int*)d_in[2];
    const float* Wq1 = (const float*)d_in[3],  *bq1 = (const float*)d_in[4];
    const float* Wk1 = (const float*)d_in[5],  *bk1 = (const float*)d_in[6];
    const float* Wv1 = (const float*)d_in[7],  *bv1 = (const float*)d_in[8];
    const float* Ws1 = (const float*)d_in[9],  *bs1 = (const float*)d_in[10];
    const float* Wq2 = (const float*)d_in[11], *bq2 = (const float*)d_in[12];
    const float* Wk2 = (const float*)d_in[13], *bk2 = (const float*)d_in[14];
    const float* Wv2 = (const float*)d_in[15], *bv2 = (const float*)d_in[16];
    const float* Ws2 = (const float*)d_in[17], *bs2 = (const float*)d_in[18];
    const float* Wlin = (const float*)d_in[19], *blin = (const float*)d_in[20];

    const int N = in_sizes[0] / 128;
    const int E = in_sizes[1] / 2;
    const int* src = ei;
    const int* dstp = ei + E;
    const int NB = (N + 1023) / 1024;
    const int Ns = (N + 127) & ~127;      // padded node stride for xT rows

    // workspace carve (256B aligned)
    char* wp = (char*)d_ws;
    auto alloc = [&](size_t bytes) -> void* {
        void* p = wp;
        wp += (bytes + 255) & ~(size_t)255;
        return p;
    };
    unsigned* qh  = (unsigned*)alloc((size_t)N * 64 * 4);   // q as half2 pairs
    uint2* kv2    = (uint2*)alloc((size_t)N * 64 * 8);      // {k2,v2} per pair
    float* skip = (float*)alloc((size_t)N * CC * 4);
    float* h1   = (float*)alloc((size_t)N * CC * 4);
    float* h2   = (float*)alloc((size_t)N * CC * 4);
    float* xT   = (float*)alloc((size_t)Ns * HC * 4);   // [128][Ns]
    float* h1T  = (float*)alloc((size_t)Ns * CC * 4);   // [32][Ns]
    int* deg    = (int*)alloc((size_t)N * 4);
    int* off    = (int*)alloc((size_t)(N + 1) * 4);
    int* cursor = (int*)alloc((size_t)N * 4);
    int* esrc   = (int*)alloc((size_t)E * 4);
    int* bsum   = (int*)alloc((size_t)((NB + 63) & ~63) * 4);
    float* sums = (float*)alloc((size_t)GG * CC * 4);
    float* cntf = (float*)alloc((size_t)GG * 4);

    const int RT = (N + 31) / 32;   // transpose row tiles

    // ---- CSR build (once; shared by both layers) ----
    hipMemsetAsync(deg, 0, (size_t)N * 4, stream);
    deg_kernel<<<(E + 255) / 256, 256, 0, stream>>>(dstp, deg, E);
    bsum_kernel<<<NB, 256, 0, stream>>>(deg, bsum, N);
    bscan_kernel<<<1, 64, 0, stream>>>(bsum, off, NB, N);
    scan2_kernel<<<NB, 256, 0, stream>>>(deg, bsum, off, cursor, N);
    fill_kernel<<<(E + 255) / 256, 256, 0, stream>>>(src, dstp, cursor, esrc, E);

    dim3 ggrid((N + 127) / 128, 7);
    dim3 agrid((N + 1) / 2);

    // ---- layer 1 ----
    transpose_kernel<<<dim3(4, RT), 256, 0, stream>>>(x, xT, N, HC, Ns);
    qkv_gemm_kernel<128><<<ggrid, 256, 0, stream>>>(xT, Ns, Wq1, bq1, Wk1, bk1, Wv1, bv1,
                                                    Ws1, bs1, qh, (unsigned*)kv2, skip, N);
    attn_kernel<<<agrid, 128, 0, stream>>>(qh, kv2, off, esrc, skip, h1, N, 1);

    // ---- layer 2 ----
    transpose_kernel<<<dim3(1, RT), 256, 0, stream>>>(h1, h1T, N, CC, Ns);
    qkv_gemm_kernel<32><<<ggrid, 256, 0, stream>>>(h1T, Ns, Wq2, bq2, Wk2, bk2, Wv2, bv2,
                                                   Ws2, bs2, qh, (unsigned*)kv2, skip, N);
    attn_kernel<<<agrid, 128, 0, stream>>>(qh, kv2, off, esrc, skip, h2, N, 0);

    // ---- pool + final linear ----
    hipMemsetAsync(sums, 0, (size_t)GG * CC * 4, stream);
    hipMemsetAsync(cntf, 0, (size_t)GG * 4, stream);
    pool_kernel<<<(N + 255) / 256, 256, 0, stream>>>(h2, batch, sums, cntf, N);
    final_lin_kernel<<<GG, 16, 0, stream>>>(sums, cntf, Wlin, blin, (float*)d_out);
}

// Round 11
// 250.597 us; speedup vs baseline: 12.8052x; 1.2611x over previous
//
#include <hip/hip_runtime.h>
#include <hip/hip_bf16.h>
#include <hip/hip_fp16.h>
#include <math.h>

#define HH 4
#define CC 32
#define HC 128   // H*C
#define GG 64

typedef _Float16 f16x2 __attribute__((ext_vector_type(2)));
typedef _Float16 f16x8 __attribute__((ext_vector_type(8)));
typedef float f32x4 __attribute__((ext_vector_type(4)));

__device__ __forceinline__ f16x2 u2h(unsigned u) {
    union { unsigned u; f16x2 h; } x; x.u = u; return x.h;
}
__device__ __forceinline__ unsigned pkh(float a, float b) {
    __half2 h = __floats2half2_rn(a, b);
    union { __half2 h; unsigned u; } x; x.h = h; return x.u;
}
__device__ __forceinline__ f16x8 uq2h8(uint4 u) {
    union { uint4 u; f16x8 h; } x; x.u = u; return x.h;
}

// ---------------- fp32 -> fp16 convert (4 elems/thread) ----------------
__global__ void cvt_f2h_kernel(const float* __restrict__ in, unsigned* __restrict__ out, int n4)
{
    int i = blockIdx.x * 256 + threadIdx.x;
    if (i < n4) {
        float4 f = ((const float4*)in)[i];
        ((uint2*)out)[i] = make_uint2(pkh(f.x, f.y), pkh(f.z, f.w));
    }
}

// ---------------- bake W into MFMA B-fragments ----------------
// wfrag[(ct*KS + ks)*64 + lane] = uint4 of 8 halves: W[ks*32 + (lane>>4)*8 + j][col(ct, lane&15)]
// ct 0-7: Wq, 8-15: Wk, 16-23: Wv, 24-25: Ws.
__global__ void wfrag_kernel(const float* __restrict__ Wq, const float* __restrict__ Wk,
                             const float* __restrict__ Wv, const float* __restrict__ Ws,
                             uint4* __restrict__ wfrag, int KS)
{
    int idx = blockIdx.x * 256 + threadIdx.x;
    int total = 26 * KS * 64;
    if (idx >= total) return;
    int lane = idx & 63;
    int t = idx >> 6;
    int ks = t % KS, ct = t / KS;
    int r = lane & 15, g = lane >> 4;
    const float* W; int c, stride;
    if (ct < 8)       { W = Wq; c = ct * 16 + r;        stride = HC; }
    else if (ct < 16) { W = Wk; c = (ct - 8) * 16 + r;  stride = HC; }
    else if (ct < 24) { W = Wv; c = (ct - 16) * 16 + r; stride = HC; }
    else              { W = Ws; c = (ct - 24) * 16 + r; stride = CC; }
    unsigned u[4];
    #pragma unroll
    for (int jj = 0; jj < 4; ++jj) {
        int k = ks * 32 + g * 8 + jj * 2;
        u[jj] = pkh(W[(size_t)k * stride + c], W[(size_t)(k + 1) * stride + c]);
    }
    wfrag[idx] = make_uint4(u[0], u[1], u[2], u[3]);
}

// ---------------- QKV + skip projection: MFMA GEMM ----------------
// grid = (ceil(N/64), 2); block 256 = 4 waves, each wave a 16-node strip.
// y-half handles 13 col-tiles of 16: global ct 0..25 (q 0-7, k 8-15, v 16-23, skip 24-25).
// A: xh fp16 row-major [*][KDIM]; lane reads 8 contiguous halves -> k-map g*8+j matches wfrag.
// D (m89-verified): col = lane&15, node = n0 + (lane>>4)*4 + reg.
template<int KDIM>
__global__ __launch_bounds__(256) void qkv_mfma_kernel(
    const ushort* __restrict__ xh, const uint4* __restrict__ wfrag,
    const float* __restrict__ bq, const float* __restrict__ bk,
    const float* __restrict__ bv, const float* __restrict__ bs,
    unsigned* __restrict__ qh, unsigned* __restrict__ kvw, float* __restrict__ skip,
    int N)
{
    constexpr int KS = KDIM / 32;
    const int lane = threadIdx.x & 63;
    const int wv = threadIdx.x >> 6;
    const int n0 = (blockIdx.x * 4 + wv) * 16;
    if (n0 >= N) return;
    const int ct0 = blockIdx.y * 13;
    const int r = lane & 15, g = lane >> 4;

    f16x8 a[KS];
    #pragma unroll
    for (int ks = 0; ks < KS; ++ks)
        a[ks] = uq2h8(*(const uint4*)&xh[(size_t)(n0 + r) * KDIM + ks * 32 + g * 8]);

    f32x4 acc[13];
    #pragma unroll
    for (int ct = 0; ct < 13; ++ct) acc[ct] = (f32x4){0.f, 0.f, 0.f, 0.f};

    #pragma unroll
    for (int ct = 0; ct < 13; ++ct)
        #pragma unroll
        for (int ks = 0; ks < KS; ++ks) {
            f16x8 bfr = uq2h8(wfrag[((size_t)(ct0 + ct) * KS + ks) * 64 + lane]);
            acc[ct] = __builtin_amdgcn_mfma_f32_16x16x32_f16(a[ks], bfr, acc[ct], 0, 0, 0);
        }

    #pragma unroll
    for (int ct = 0; ct < 13; ++ct) {
        int gct = ct0 + ct;
        int c = gct * 16 + r;            // global col 0..415
        if (gct < 24) {                  // q / k / v -> half2-pair stores
            float bb = (gct < 8) ? bq[c] : (gct < 16) ? bk[c - 128] : bv[c - 256];
            int ch = (gct < 8) ? c : (gct < 16) ? (c - 128) : (c - 256);
            #pragma unroll
            for (int reg = 0; reg < 4; ++reg) {
                int node = n0 + g * 4 + reg;
                float val = acc[ct][reg] + bb;
                unsigned hv = __half_as_ushort(__float2half(val));
                unsigned other = (unsigned)__shfl_xor((int)hv, 1, 64);
                if (!(lane & 1) && node < N) {
                    unsigned pair = hv | (other << 16);
                    size_t p = (size_t)node * 64 + (ch >> 1);
                    if (gct < 8)       qh[p]          = pair;
                    else if (gct < 16) kvw[p * 2]     = pair;
                    else               kvw[p * 2 + 1] = pair;
                }
            }
        } else {                          // skip (fp32)
            int cs = c - 384;
            float bb = bs[cs];
            #pragma unroll
            for (int reg = 0; reg < 4; ++reg) {
                int node = n0 + g * 4 + reg;
                if (node < N) skip[(size_t)node * CC + cs] = acc[ct][reg] + bb;
            }
        }
    }
}

// ---------------- CSR build ----------------
__global__ void deg_kernel(const int* __restrict__ dst, int* __restrict__ deg, int E)
{
    int e = blockIdx.x * blockDim.x + threadIdx.x;
    if (e < E) atomicAdd(&deg[dst[e]], 1);
}

__global__ void bsum_kernel(const int* __restrict__ deg, int* __restrict__ bsum, int N)
{
    int base = blockIdx.x * 1024;
    int tid = threadIdx.x;  // 256
    int s = 0;
    for (int i = base + tid; i < base + 1024 && i < N; i += 256) s += deg[i];
    #pragma unroll
    for (int ofs = 32; ofs > 0; ofs >>= 1) s += __shfl_xor(s, ofs, 64);
    __shared__ int ws[4];
    int wid = tid >> 6;
    if ((tid & 63) == 0) ws[wid] = s;
    __syncthreads();
    if (tid == 0) bsum[blockIdx.x] = ws[0] + ws[1] + ws[2] + ws[3];
}

__global__ void bscan_kernel(int* __restrict__ bsum, int* __restrict__ off, int nb, int N)
{
    int i = threadIdx.x;   // 64
    int val = (i < nb) ? bsum[i] : 0;
    int v = val;
    #pragma unroll
    for (int ofs = 1; ofs < 64; ofs <<= 1) {
        int t = __shfl_up(v, ofs, 64);
        if (i >= ofs) v += t;
    }
    if (i < nb) bsum[i] = v - val;   // exclusive
    if (i == 63) off[N] = v;         // grand total
}

__global__ void scan2_kernel(const int* __restrict__ deg, const int* __restrict__ bsum,
                             int* __restrict__ off, int* __restrict__ cursor, int N)
{
    int base = blockIdx.x * 1024;
    int tid = threadIdx.x;          // 256
    int idx = base + tid * 4;
    int d0 = (idx     < N) ? deg[idx]     : 0;
    int d1 = (idx + 1 < N) ? deg[idx + 1] : 0;
    int d2 = (idx + 2 < N) ? deg[idx + 2] : 0;
    int d3 = (idx + 3 < N) ? deg[idx + 3] : 0;
    int tsum = d0 + d1 + d2 + d3;
    int v = tsum;
    int lane = tid & 63;
    #pragma unroll
    for (int ofs = 1; ofs < 64; ofs <<= 1) {
        int t = __shfl_up(v, ofs, 64);
        if (lane >= ofs) v += t;
    }
    __shared__ int wsum[4];
    int wid = tid >> 6;
    if (lane == 63) wsum[wid] = v;
    __syncthreads();
    int wbase = 0;
    for (int w = 0; w < wid; ++w) wbase += wsum[w];
    int excl = bsum[blockIdx.x] + wbase + (v - tsum);
    if (idx     < N) { off[idx]     = excl;                cursor[idx]     = excl; }
    if (idx + 1 < N) { off[idx + 1] = excl + d0;           cursor[idx + 1] = excl + d0; }
    if (idx + 2 < N) { off[idx + 2] = excl + d0 + d1;      cursor[idx + 2] = excl + d0 + d1; }
    if (idx + 3 < N) { off[idx + 3] = excl + d0 + d1 + d2; cursor[idx + 3] = excl + d0 + d1 + d2; }
}

__global__ void fill_kernel(const int* __restrict__ src, const int* __restrict__ dst,
                            int* __restrict__ cursor, int* __restrict__ esrc, int E)
{
    int e = blockIdx.x * blockDim.x + threadIdx.x;
    if (e < E) {
        int d = dst[e];
        int pos = atomicAdd(&cursor[d], 1);
        esrc[pos] = src[e];
    }
}

// ---------------- fused attention: 1 wave per node ----------------
// MODE 1: relu + fp16 (u32-pair) output; MODE 0: fp32 output.
template<int MODE>
__global__ __launch_bounds__(128) void attn_kernel(const unsigned* __restrict__ qh,
    const uint2* __restrict__ kv2, const int* __restrict__ off, const int* __restrict__ esrc,
    const float* __restrict__ skip, void* __restrict__ hout, int N)
{
    const int wave = threadIdx.x >> 6;
    const int lane = threadIdx.x & 63;
    const int n = blockIdx.x * 2 + wave;
    if (n >= N) return;
    const int c2 = lane & 15;
    const float scale = 0.17677669529663687f;  // 1/sqrt(32)

    f16x2 q2 = u2h(qh[(size_t)n * 64 + lane]);
    int beg = __builtin_amdgcn_readfirstlane(off[n]);
    int end = __builtin_amdgcn_readfirstlane(off[n + 1]);

    float lsum = 0.f, ax = 0.f, ay = 0.f;

    auto body = [&](uint2 raw) {
        f16x2 k2 = u2h(raw.x), v2 = u2h(raw.y);
#if defined(__has_builtin) && __has_builtin(__builtin_amdgcn_fdot2)
        float d = __builtin_amdgcn_fdot2(q2, k2, 0.f, false);
#else
        float d = (float)q2.x * (float)k2.x + (float)q2.y * (float)k2.y;
#endif
        d += __shfl_xor(d, 1, 16);
        d += __shfl_xor(d, 2, 16);
        d += __shfl_xor(d, 4, 16);
        d += __shfl_xor(d, 8, 16);
        float e = __expf(d * scale);
        lsum += e;
        ax = fmaf(e, (float)v2.x, ax);
        ay = fmaf(e, (float)v2.y, ay);
    };

    int p = beg;
    for (; p + 4 <= end; p += 4) {
        int s0 = esrc[p], s1 = esrc[p + 1], s2 = esrc[p + 2], s3 = esrc[p + 3];
        uint2 r0 = kv2[(size_t)s0 * 64 + lane];
        uint2 r1 = kv2[(size_t)s1 * 64 + lane];
        uint2 r2 = kv2[(size_t)s2 * 64 + lane];
        uint2 r3 = kv2[(size_t)s3 * 64 + lane];
        body(r0); body(r1); body(r2); body(r3);
    }
    for (; p < end; ++p) {
        int s0 = esrc[p];
        body(kv2[(size_t)s0 * 64 + lane]);
    }

    float inv = 1.f / (lsum + 1e-16f);
    float rx = ax * inv, ry = ay * inv;
    rx += __shfl_xor(rx, 16, 64);  ry += __shfl_xor(ry, 16, 64);
    rx += __shfl_xor(rx, 32, 64);  ry += __shfl_xor(ry, 32, 64);
    if (lane < 16) {
        float2 sk = *(const float2*)&skip[(size_t)n * CC + c2 * 2];
        float ox = 0.25f * rx + sk.x;
        float oy = 0.25f * ry + sk.y;
        if (MODE) {
            ox = fmaxf(ox, 0.f); oy = fmaxf(oy, 0.f);
            ((unsigned*)hout)[(size_t)n * 16 + c2] = pkh(ox, oy);
        } else {
            *(float2*)&((float*)hout)[(size_t)n * CC + c2 * 2] = make_float2(ox, oy);
        }
    }
}

// ---------------- global mean pool (sorted-run accumulation) ----------------
__global__ void pool_kernel(const float* __restrict__ h, const int* __restrict__ batch,
    float* __restrict__ sums, float* __restrict__ cntf, int N)
{
    int c = threadIdx.x & 31;
    int tn = threadIdx.x >> 5;            // 0..7
    int n0 = blockIdx.x * 256;
    int nend = (n0 + 256 < N) ? n0 + 256 : N;
    float acc = 0.f, cnt = 0.f;
    int curg = -1;
    for (int n = n0 + tn; n < nend; n += 8) {
        int g = batch[n];
        if (g != curg) {
            if (curg >= 0) {
                unsafeAtomicAdd(&sums[curg * CC + c], acc);
                if (c == 0) unsafeAtomicAdd(&cntf[curg], cnt);
            }
            acc = 0.f; cnt = 0.f; curg = g;
        }
        acc += h[(size_t)n * CC + c];
        cnt += 1.f;
    }
    if (curg >= 0) {
        unsafeAtomicAdd(&sums[curg * CC + c], acc);
        if (c == 0) unsafeAtomicAdd(&cntf[curg], cnt);
    }
}

// ---------------- final linear ----------------
__global__ void final_lin_kernel(const float* __restrict__ sums, const float* __restrict__ cntf,
    const float* __restrict__ Wlin, const float* __restrict__ blin, float* __restrict__ out)
{
    int g = blockIdx.x;        // 64
    int j = threadIdx.x;       // 16
    float cnt = fmaxf(cntf[g], 1.0f);
    float acc = 0.f;
    #pragma unroll
    for (int c = 0; c < CC; ++c)
        acc += (sums[g * CC + c] / cnt) * Wlin[c * 16 + j];
    out[g * 16 + j] = acc + blin[j];
}

extern "C" void kernel_launch(void* const* d_in, const int* in_sizes, int n_in,
                              void* d_out, int out_size, void* d_ws, size_t ws_size,
                              hipStream_t stream) {
    const float* x     = (const float*)d_in[0];
    const int*   ei    = (const int*)d_in[1];
    const int*   batch = (const int*)d_in[2];
    const float* Wq1 = (const float*)d_in[3],  *bq1 = (const float*)d_in[4];
    const float* Wk1 = (const float*)d_in[5],  *bk1 = (const float*)d_in[6];
    const float* Wv1 = (const float*)d_in[7],  *bv1 = (const float*)d_in[8];
    const float* Ws1 = (const float*)d_in[9],  *bs1 = (const float*)d_in[10];
    const float* Wq2 = (const float*)d_in[11], *bq2 = (const float*)d_in[12];
    const float* Wk2 = (const float*)d_in[13], *bk2 = (const float*)d_in[14];
    const float* Wv2 = (const float*)d_in[15], *bv2 = (const float*)d_in[16];
    const float* Ws2 = (const float*)d_in[17], *bs2 = (const float*)d_in[18];
    const float* Wlin = (const float*)d_in[19], *blin = (const float*)d_in[20];

    const int N = in_sizes[0] / 128;
    const int E = in_sizes[1] / 2;
    const int* src = ei;
    const int* dstp = ei + E;
    const int NB = (N + 1023) / 1024;
    const int Npad = (N + 63) & ~63;

    // workspace carve (256B aligned)
    char* wp = (char*)d_ws;
    auto alloc = [&](size_t bytes) -> void* {
        void* p = wp;
        wp += (bytes + 255) & ~(size_t)255;
        return p;
    };
    unsigned* qh   = (unsigned*)alloc((size_t)N * 64 * 4);    // q half2 pairs
    uint2* kv2     = (uint2*)alloc((size_t)N * 64 * 8);       // {k2,v2} pairs
    float* skip    = (float*)alloc((size_t)N * CC * 4);
    unsigned* h1h  = (unsigned*)alloc((size_t)Npad * 16 * 4); // h1 fp16 pairs [N][16]
    float* h2      = (float*)alloc((size_t)N * CC * 4);
    ushort* xh     = (ushort*)alloc((size_t)Npad * HC * 2);   // x fp16
    uint4* wfrag1  = (uint4*)alloc((size_t)26 * 4 * 64 * 16);
    uint4* wfrag2  = (uint4*)alloc((size_t)26 * 1 * 64 * 16);
    int* deg    = (int*)alloc((size_t)N * 4);
    int* off    = (int*)alloc((size_t)(N + 1) * 4);
    int* cursor = (int*)alloc((size_t)N * 4);
    int* esrc   = (int*)alloc((size_t)E * 4);
    int* bsum   = (int*)alloc((size_t)((NB + 63) & ~63) * 4);
    float* sums = (float*)alloc((size_t)GG * CC * 4);
    float* cntf = (float*)alloc((size_t)GG * 4);

    // ---- prep: x->fp16, weight fragments ----
    cvt_f2h_kernel<<<(N * HC / 4 + 255) / 256, 256, 0, stream>>>(x, (unsigned*)xh, N * HC / 4);
    wfrag_kernel<<<(26 * 4 * 64 + 255) / 256, 256, 0, stream>>>(Wq1, Wk1, Wv1, Ws1, wfrag1, 4);
    wfrag_kernel<<<(26 * 1 * 64 + 255) / 256, 256, 0, stream>>>(Wq2, Wk2, Wv2, Ws2, wfrag2, 1);

    // ---- CSR build (once; shared by both layers) ----
    hipMemsetAsync(deg, 0, (size_t)N * 4, stream);
    deg_kernel<<<(E + 255) / 256, 256, 0, stream>>>(dstp, deg, E);
    bsum_kernel<<<NB, 256, 0, stream>>>(deg, bsum, N);
    bscan_kernel<<<1, 64, 0, stream>>>(bsum, off, NB, N);
    scan2_kernel<<<NB, 256, 0, stream>>>(deg, bsum, off, cursor, N);
    fill_kernel<<<(E + 255) / 256, 256, 0, stream>>>(src, dstp, cursor, esrc, E);

    dim3 ggrid((N + 63) / 64, 2);
    dim3 agrid((N + 1) / 2);

    // ---- layer 1 ----
    qkv_mfma_kernel<128><<<ggrid, 256, 0, stream>>>(xh, wfrag1, bq1, bk1, bv1, bs1,
                                                    qh, (unsigned*)kv2, skip, N);
    attn_kernel<1><<<agrid, 128, 0, stream>>>(qh, kv2, off, esrc, skip, h1h, N);

    // ---- layer 2 ----
    qkv_mfma_kernel<32><<<ggrid, 256, 0, stream>>>((const ushort*)h1h, wfrag2, bq2, bk2, bv2, bs2,
                                                   qh, (unsigned*)kv2, skip, N);
    attn_kernel<0><<<agrid, 128, 0, stream>>>(qh, kv2, off, esrc, skip, h2, N);

    // ---- pool + final linear ----
    hipMemsetAsync(sums, 0, (size_t)GG * CC * 4, stream);
    hipMemsetAsync(cntf, 0, (size_t)GG * 4, stream);
    pool_kernel<<<(N + 255) / 256, 256, 0, stream>>>(h2, batch, sums, cntf, N);
    final_lin_kernel<<<GG, 16, 0, stream>>>(sums, cntf, Wlin, blin, (float*)d_out);
}

// Round 12
// 238.846 us; speedup vs baseline: 13.4352x; 1.0492x over previous
//
#include <hip/hip_runtime.h>
#include <hip/hip_bf16.h>
#include <hip/hip_fp16.h>
#include <math.h>

#define HH 4
#define CC 32
#define HC 128   // H*C
#define GG 64

typedef _Float16 f16x2 __attribute__((ext_vector_type(2)));
typedef _Float16 f16x8 __attribute__((ext_vector_type(8)));
typedef float f32x4 __attribute__((ext_vector_type(4)));

__device__ __forceinline__ f16x2 u2h(unsigned u) {
    union { unsigned u; f16x2 h; } x; x.u = u; return x.h;
}
__device__ __forceinline__ unsigned pkh(float a, float b) {
    __half2 h = __floats2half2_rn(a, b);
    union { __half2 h; unsigned u; } x; x.h = h; return x.u;
}
__device__ __forceinline__ f16x8 uq2h8(uint4 u) {
    union { uint4 u; f16x8 h; } x; x.u = u; return x.h;
}

// ---------------- fp32 -> fp16 convert (4 elems/thread) ----------------
__global__ void cvt_f2h_kernel(const float* __restrict__ in, unsigned* __restrict__ out, int n4)
{
    int i = blockIdx.x * 256 + threadIdx.x;
    if (i < n4) {
        float4 f = ((const float4*)in)[i];
        ((uint2*)out)[i] = make_uint2(pkh(f.x, f.y), pkh(f.z, f.w));
    }
}

// ---------------- bake W into MFMA fragments ----------------
// wfrag[(ct*KS + ks)*64 + lane] = 8 halves: W[ks*32 + (lane>>4)*8 + j][ct*16 + (lane&15)]
// ct 0-7: Wq, 8-15: Wk, 16-23: Wv, 24-25: Ws.
__global__ void wfrag_kernel(const float* __restrict__ Wq, const float* __restrict__ Wk,
                             const float* __restrict__ Wv, const float* __restrict__ Ws,
                             uint4* __restrict__ wfrag, int KS)
{
    int idx = blockIdx.x * 256 + threadIdx.x;
    int total = 26 * KS * 64;
    if (idx >= total) return;
    int lane = idx & 63;
    int t = idx >> 6;
    int ks = t % KS, ct = t / KS;
    int r = lane & 15, g = lane >> 4;
    const float* W; int c, stride;
    if (ct < 8)       { W = Wq; c = ct * 16 + r;        stride = HC; }
    else if (ct < 16) { W = Wk; c = (ct - 8) * 16 + r;  stride = HC; }
    else if (ct < 24) { W = Wv; c = (ct - 16) * 16 + r; stride = HC; }
    else              { W = Ws; c = (ct - 24) * 16 + r; stride = CC; }
    unsigned u[4];
    #pragma unroll
    for (int jj = 0; jj < 4; ++jj) {
        int k = ks * 32 + g * 8 + jj * 2;
        u[jj] = pkh(W[(size_t)k * stride + c], W[(size_t)(k + 1) * stride + c]);
    }
    wfrag[idx] = make_uint4(u[0], u[1], u[2], u[3]);
}

// ---------------- QKV + skip projection: MFMA GEMM (operand-swapped) ----------------
// grid = (ceil(N/64), 2); block 256 = 4 waves, each wave a 16-node strip.
// mfma(W-frag, x-frag): D = out[node = n0+(lane&15)][col = ct*16 + g*4 + reg]
//   -> per lane: ONE node, 4 consecutive cols => fully vectorized stores, no shfl.
// y=0: q (ct 0..7) + skip (ct 24,25);  y=1: k (ct 8..15) + v (ct 16..23),
//   interleaved kv row written as one uint4 {k01,v01,k23,v23} per ct.
template<int KDIM>
__global__ __launch_bounds__(256) void qkv_mfma_kernel(
    const ushort* __restrict__ xh, const uint4* __restrict__ wfrag,
    const float* __restrict__ bq, const float* __restrict__ bk,
    const float* __restrict__ bv, const float* __restrict__ bs,
    unsigned* __restrict__ qh, unsigned* __restrict__ kvw, float* __restrict__ skip,
    int N)
{
    constexpr int KS = KDIM / 32;
    const int lane = threadIdx.x & 63;
    const int wv = threadIdx.x >> 6;
    const int n0 = (blockIdx.x * 4 + wv) * 16;
    if (n0 >= N) return;
    const int r = lane & 15, g = lane >> 4;
    const int node = n0 + r;

    f16x8 a[KS];
    #pragma unroll
    for (int ks = 0; ks < KS; ++ks)
        a[ks] = uq2h8(*(const uint4*)&xh[(size_t)node * KDIM + ks * 32 + g * 8]);

    if (blockIdx.y == 0) {
        // ---- q (8 tiles) + skip (2 tiles) ----
        f32x4 acc[10];
        #pragma unroll
        for (int i = 0; i < 10; ++i) acc[i] = (f32x4){0.f, 0.f, 0.f, 0.f};
        #pragma unroll
        for (int i = 0; i < 8; ++i)
            #pragma unroll
            for (int ks = 0; ks < KS; ++ks) {
                f16x8 w = uq2h8(wfrag[((size_t)i * KS + ks) * 64 + lane]);
                acc[i] = __builtin_amdgcn_mfma_f32_16x16x32_f16(w, a[ks], acc[i], 0, 0, 0);
            }
        #pragma unroll
        for (int i = 0; i < 2; ++i)
            #pragma unroll
            for (int ks = 0; ks < KS; ++ks) {
                f16x8 w = uq2h8(wfrag[((size_t)(24 + i) * KS + ks) * 64 + lane]);
                acc[8 + i] = __builtin_amdgcn_mfma_f32_16x16x32_f16(w, a[ks], acc[8 + i], 0, 0, 0);
            }
        if (node < N) {
            #pragma unroll
            for (int i = 0; i < 8; ++i) {
                float4 bb = *(const float4*)&bq[i * 16 + g * 4];
                uint2 o = make_uint2(pkh(acc[i][0] + bb.x, acc[i][1] + bb.y),
                                     pkh(acc[i][2] + bb.z, acc[i][3] + bb.w));
                *(uint2*)&qh[(size_t)node * 64 + i * 8 + g * 2] = o;
            }
            #pragma unroll
            for (int i = 0; i < 2; ++i) {
                float4 bb = *(const float4*)&bs[i * 16 + g * 4];
                float4 o = make_float4(acc[8 + i][0] + bb.x, acc[8 + i][1] + bb.y,
                                       acc[8 + i][2] + bb.z, acc[8 + i][3] + bb.w);
                *(float4*)&skip[(size_t)node * CC + i * 16 + g * 4] = o;
            }
        }
    } else {
        // ---- k (8 tiles) + v (8 tiles) ----
        f32x4 acck[8], accv[8];
        #pragma unroll
        for (int i = 0; i < 8; ++i) { acck[i] = (f32x4){0.f,0.f,0.f,0.f}; accv[i] = (f32x4){0.f,0.f,0.f,0.f}; }
        #pragma unroll
        for (int i = 0; i < 8; ++i)
            #pragma unroll
            for (int ks = 0; ks < KS; ++ks) {
                f16x8 wk = uq2h8(wfrag[((size_t)(8 + i) * KS + ks) * 64 + lane]);
                acck[i] = __builtin_amdgcn_mfma_f32_16x16x32_f16(wk, a[ks], acck[i], 0, 0, 0);
                f16x8 wvf = uq2h8(wfrag[((size_t)(16 + i) * KS + ks) * 64 + lane]);
                accv[i] = __builtin_amdgcn_mfma_f32_16x16x32_f16(wvf, a[ks], accv[i], 0, 0, 0);
            }
        if (node < N) {
            #pragma unroll
            for (int i = 0; i < 8; ++i) {
                float4 bbk = *(const float4*)&bk[i * 16 + g * 4];
                float4 bbv = *(const float4*)&bv[i * 16 + g * 4];
                uint4 o;
                o.x = pkh(acck[i][0] + bbk.x, acck[i][1] + bbk.y);
                o.y = pkh(accv[i][0] + bbv.x, accv[i][1] + bbv.y);
                o.z = pkh(acck[i][2] + bbk.z, acck[i][3] + bbk.w);
                o.w = pkh(accv[i][2] + bbv.z, accv[i][3] + bbv.w);
                *(uint4*)&kvw[(size_t)node * 128 + i * 16 + g * 4] = o;
            }
        }
    }
}

// ---------------- CSR build ----------------
__global__ void deg_kernel(const int* __restrict__ dst, int* __restrict__ deg, int E)
{
    int e = blockIdx.x * blockDim.x + threadIdx.x;
    if (e < E) atomicAdd(&deg[dst[e]], 1);
}

__global__ void bsum_kernel(const int* __restrict__ deg, int* __restrict__ bsum, int N)
{
    int base = blockIdx.x * 1024;
    int tid = threadIdx.x;  // 256
    int s = 0;
    for (int i = base + tid; i < base + 1024 && i < N; i += 256) s += deg[i];
    #pragma unroll
    for (int ofs = 32; ofs > 0; ofs >>= 1) s += __shfl_xor(s, ofs, 64);
    __shared__ int ws[4];
    int wid = tid >> 6;
    if ((tid & 63) == 0) ws[wid] = s;
    __syncthreads();
    if (tid == 0) bsum[blockIdx.x] = ws[0] + ws[1] + ws[2] + ws[3];
}

__global__ void bscan_kernel(int* __restrict__ bsum, int* __restrict__ off, int nb, int N)
{
    int i = threadIdx.x;   // 64
    int val = (i < nb) ? bsum[i] : 0;
    int v = val;
    #pragma unroll
    for (int ofs = 1; ofs < 64; ofs <<= 1) {
        int t = __shfl_up(v, ofs, 64);
        if (i >= ofs) v += t;
    }
    if (i < nb) bsum[i] = v - val;   // exclusive
    if (i == 63) off[N] = v;         // grand total
}

__global__ void scan2_kernel(const int* __restrict__ deg, const int* __restrict__ bsum,
                             int* __restrict__ off, int* __restrict__ cursor, int N)
{
    int base = blockIdx.x * 1024;
    int tid = threadIdx.x;          // 256
    int idx = base + tid * 4;
    int d0 = (idx     < N) ? deg[idx]     : 0;
    int d1 = (idx + 1 < N) ? deg[idx + 1] : 0;
    int d2 = (idx + 2 < N) ? deg[idx + 2] : 0;
    int d3 = (idx + 3 < N) ? deg[idx + 3] : 0;
    int tsum = d0 + d1 + d2 + d3;
    int v = tsum;
    int lane = tid & 63;
    #pragma unroll
    for (int ofs = 1; ofs < 64; ofs <<= 1) {
        int t = __shfl_up(v, ofs, 64);
        if (lane >= ofs) v += t;
    }
    __shared__ int wsum[4];
    int wid = tid >> 6;
    if (lane == 63) wsum[wid] = v;
    __syncthreads();
    int wbase = 0;
    for (int w = 0; w < wid; ++w) wbase += wsum[w];
    int excl = bsum[blockIdx.x] + wbase + (v - tsum);
    if (idx     < N) { off[idx]     = excl;                cursor[idx]     = excl; }
    if (idx + 1 < N) { off[idx + 1] = excl + d0;           cursor[idx + 1] = excl + d0; }
    if (idx + 2 < N) { off[idx + 2] = excl + d0 + d1;      cursor[idx + 2] = excl + d0 + d1; }
    if (idx + 3 < N) { off[idx + 3] = excl + d0 + d1 + d2; cursor[idx + 3] = excl + d0 + d1 + d2; }
}

__global__ void fill_kernel(const int* __restrict__ src, const int* __restrict__ dst,
                            int* __restrict__ cursor, int* __restrict__ esrc, int E)
{
    int e = blockIdx.x * blockDim.x + threadIdx.x;
    if (e < E) {
        int d = dst[e];
        int pos = atomicAdd(&cursor[d], 1);
        esrc[pos] = src[e];
    }
}

// ---------------- fused attention: 1 wave per node ----------------
// MODE 1: relu + fp16 (u32-pair) output; MODE 0: fp32 output.
template<int MODE>
__global__ __launch_bounds__(128) void attn_kernel(const unsigned* __restrict__ qh,
    const uint2* __restrict__ kv2, const int* __restrict__ off, const int* __restrict__ esrc,
    const float* __restrict__ skip, void* __restrict__ hout, int N)
{
    const int wave = threadIdx.x >> 6;
    const int lane = threadIdx.x & 63;
    const int n = blockIdx.x * 2 + wave;
    if (n >= N) return;
    const int c2 = lane & 15;
    const float scale = 0.17677669529663687f;  // 1/sqrt(32)

    f16x2 q2 = u2h(qh[(size_t)n * 64 + lane]);
    int beg = __builtin_amdgcn_readfirstlane(off[n]);
    int end = __builtin_amdgcn_readfirstlane(off[n + 1]);

    float lsum = 0.f, ax = 0.f, ay = 0.f;

    auto body = [&](uint2 raw) {
        f16x2 k2 = u2h(raw.x), v2 = u2h(raw.y);
#if defined(__has_builtin) && __has_builtin(__builtin_amdgcn_fdot2)
        float d = __builtin_amdgcn_fdot2(q2, k2, 0.f, false);
#else
        float d = (float)q2.x * (float)k2.x + (float)q2.y * (float)k2.y;
#endif
        d += __shfl_xor(d, 1, 16);
        d += __shfl_xor(d, 2, 16);
        d += __shfl_xor(d, 4, 16);
        d += __shfl_xor(d, 8, 16);
        float e = __expf(d * scale);
        lsum += e;
        ax = fmaf(e, (float)v2.x, ax);
        ay = fmaf(e, (float)v2.y, ay);
    };

    int p = beg;
    for (; p + 4 <= end; p += 4) {
        int s0 = esrc[p], s1 = esrc[p + 1], s2 = esrc[p + 2], s3 = esrc[p + 3];
        uint2 r0 = kv2[(size_t)s0 * 64 + lane];
        uint2 r1 = kv2[(size_t)s1 * 64 + lane];
        uint2 r2 = kv2[(size_t)s2 * 64 + lane];
        uint2 r3 = kv2[(size_t)s3 * 64 + lane];
        body(r0); body(r1); body(r2); body(r3);
    }
    for (; p < end; ++p) {
        int s0 = esrc[p];
        body(kv2[(size_t)s0 * 64 + lane]);
    }

    float inv = 1.f / (lsum + 1e-16f);
    float rx = ax * inv, ry = ay * inv;
    rx += __shfl_xor(rx, 16, 64);  ry += __shfl_xor(ry, 16, 64);
    rx += __shfl_xor(rx, 32, 64);  ry += __shfl_xor(ry, 32, 64);
    if (lane < 16) {
        float2 sk = *(const float2*)&skip[(size_t)n * CC + c2 * 2];
        float ox = 0.25f * rx + sk.x;
        float oy = 0.25f * ry + sk.y;
        if (MODE) {
            ox = fmaxf(ox, 0.f); oy = fmaxf(oy, 0.f);
            ((unsigned*)hout)[(size_t)n * 16 + c2] = pkh(ox, oy);
        } else {
            *(float2*)&((float*)hout)[(size_t)n * CC + c2 * 2] = make_float2(ox, oy);
        }
    }
}

// ---------------- global mean pool (sorted-run accumulation) ----------------
__global__ void pool_kernel(const float* __restrict__ h, const int* __restrict__ batch,
    float* __restrict__ sums, float* __restrict__ cntf, int N)
{
    int c = threadIdx.x & 31;
    int tn = threadIdx.x >> 5;            // 0..7
    int n0 = blockIdx.x * 256;
    int nend = (n0 + 256 < N) ? n0 + 256 : N;
    float acc = 0.f, cnt = 0.f;
    int curg = -1;
    for (int n = n0 + tn; n < nend; n += 8) {
        int g = batch[n];
        if (g != curg) {
            if (curg >= 0) {
                unsafeAtomicAdd(&sums[curg * CC + c], acc);
                if (c == 0) unsafeAtomicAdd(&cntf[curg], cnt);
            }
            acc = 0.f; cnt = 0.f; curg = g;
        }
        acc += h[(size_t)n * CC + c];
        cnt += 1.f;
    }
    if (curg >= 0) {
        unsafeAtomicAdd(&sums[curg * CC + c], acc);
        if (c == 0) unsafeAtomicAdd(&cntf[curg], cnt);
    }
}

// ---------------- final linear ----------------
__global__ void final_lin_kernel(const float* __restrict__ sums, const float* __restrict__ cntf,
    const float* __restrict__ Wlin, const float* __restrict__ blin, float* __restrict__ out)
{
    int g = blockIdx.x;        // 64
    int j = threadIdx.x;       // 16
    float cnt = fmaxf(cntf[g], 1.0f);
    float acc = 0.f;
    #pragma unroll
    for (int c = 0; c < CC; ++c)
        acc += (sums[g * CC + c] / cnt) * Wlin[c * 16 + j];
    out[g * 16 + j] = acc + blin[j];
}

extern "C" void kernel_launch(void* const* d_in, const int* in_sizes, int n_in,
                              void* d_out, int out_size, void* d_ws, size_t ws_size,
                              hipStream_t stream) {
    const float* x     = (const float*)d_in[0];
    const int*   ei    = (const int*)d_in[1];
    const int*   batch = (const int*)d_in[2];
    const float* Wq1 = (const float*)d_in[3],  *bq1 = (const float*)d_in[4];
    const float* Wk1 = (const float*)d_in[5],  *bk1 = (const float*)d_in[6];
    const float* Wv1 = (const float*)d_in[7],  *bv1 = (const float*)d_in[8];
    const float* Ws1 = (const float*)d_in[9],  *bs1 = (const float*)d_in[10];
    const float* Wq2 = (const float*)d_in[11], *bq2 = (const float*)d_in[12];
    const float* Wk2 = (const float*)d_in[13], *bk2 = (const float*)d_in[14];
    const float* Wv2 = (const float*)d_in[15], *bv2 = (const float*)d_in[16];
    const float* Ws2 = (const float*)d_in[17], *bs2 = (const float*)d_in[18];
    const float* Wlin = (const float*)d_in[19], *blin = (const float*)d_in[20];

    const int N = in_sizes[0] / 128;
    const int E = in_sizes[1] / 2;
    const int* src = ei;
    const int* dstp = ei + E;
    const int NB = (N + 1023) / 1024;
    const int Npad = (N + 63) & ~63;

    // workspace carve (256B aligned)
    char* wp = (char*)d_ws;
    auto alloc = [&](size_t bytes) -> void* {
        void* p = wp;
        wp += (bytes + 255) & ~(size_t)255;
        return p;
    };
    unsigned* qh   = (unsigned*)alloc((size_t)N * 64 * 4);    // q half2 pairs
    uint2* kv2     = (uint2*)alloc((size_t)N * 64 * 8);       // {k2,v2} pairs
    float* skip    = (float*)alloc((size_t)N * CC * 4);
    unsigned* h1h  = (unsigned*)alloc((size_t)Npad * 16 * 4); // h1 fp16 pairs [N][16]
    float* h2      = (float*)alloc((size_t)N * CC * 4);
    ushort* xh     = (ushort*)alloc((size_t)Npad * HC * 2);   // x fp16
    uint4* wfrag1  = (uint4*)alloc((size_t)26 * 4 * 64 * 16);
    uint4* wfrag2  = (uint4*)alloc((size_t)26 * 1 * 64 * 16);
    int* deg    = (int*)alloc((size_t)N * 4);
    int* off    = (int*)alloc((size_t)(N + 1) * 4);
    int* cursor = (int*)alloc((size_t)N * 4);
    int* esrc   = (int*)alloc((size_t)E * 4);
    int* bsum   = (int*)alloc((size_t)((NB + 63) & ~63) * 4);
    float* sums = (float*)alloc((size_t)GG * CC * 4);
    float* cntf = (float*)alloc((size_t)GG * 4);

    // ---- prep: x->fp16, weight fragments ----
    cvt_f2h_kernel<<<(N * HC / 4 + 255) / 256, 256, 0, stream>>>(x, (unsigned*)xh, N * HC / 4);
    wfrag_kernel<<<(26 * 4 * 64 + 255) / 256, 256, 0, stream>>>(Wq1, Wk1, Wv1, Ws1, wfrag1, 4);
    wfrag_kernel<<<(26 * 1 * 64 + 255) / 256, 256, 0, stream>>>(Wq2, Wk2, Wv2, Ws2, wfrag2, 1);

    // ---- CSR build (once; shared by both layers) ----
    hipMemsetAsync(deg, 0, (size_t)N * 4, stream);
    deg_kernel<<<(E + 255) / 256, 256, 0, stream>>>(dstp, deg, E);
    bsum_kernel<<<NB, 256, 0, stream>>>(deg, bsum, N);
    bscan_kernel<<<1, 64, 0, stream>>>(bsum, off, NB, N);
    scan2_kernel<<<NB, 256, 0, stream>>>(deg, bsum, off, cursor, N);
    fill_kernel<<<(E + 255) / 256, 256, 0, stream>>>(src, dstp, cursor, esrc, E);

    dim3 ggrid((N + 63) / 64, 2);
    dim3 agrid((N + 1) / 2);

    // ---- layer 1 ----
    qkv_mfma_kernel<128><<<ggrid, 256, 0, stream>>>(xh, wfrag1, bq1, bk1, bv1, bs1,
                                                    qh, (unsigned*)kv2, skip, N);
    attn_kernel<1><<<agrid, 128, 0, stream>>>(qh, kv2, off, esrc, skip, h1h, N);

    // ---- layer 2 ----
    qkv_mfma_kernel<32><<<ggrid, 256, 0, stream>>>((const ushort*)h1h, wfrag2, bq2, bk2, bv2, bs2,
                                                   qh, (unsigned*)kv2, skip, N);
    attn_kernel<0><<<agrid, 128, 0, stream>>>(qh, kv2, off, esrc, skip, h2, N);

    // ---- pool + final linear ----
    hipMemsetAsync(sums, 0, (size_t)GG * CC * 4, stream);
    hipMemsetAsync(cntf, 0, (size_t)GG * 4, stream);
    pool_kernel<<<(N + 255) / 256, 256, 0, stream>>>(h2, batch, sums, cntf, N);
    final_lin_kernel<<<GG, 16, 0, stream>>>(sums, cntf, Wlin, blin, (float*)d_out);
}